// Round 22
// baseline (437.572 us; speedup 1.0000x reference)
//
#include <hip/hip_runtime.h>
#include <hip/hip_bf16.h>
#include <stdint.h>

#define EDGES 65536

typedef unsigned int uint;
typedef unsigned short ushort;
using bf16x8 = __attribute__((ext_vector_type(8))) __bf16;
using f32x4  = __attribute__((ext_vector_type(4))) float;
using uintx4 = __attribute__((ext_vector_type(4))) uint;
using float4v = __attribute__((ext_vector_type(4))) float;
using float2v = __attribute__((ext_vector_type(2))) float;

#define C_OLD 0.8944271909999159f
#define C_NEW 0.4472135954999579f
#define T_SCALE 0.08838834764831845f

__device__ __forceinline__ ushort f2bf(float f) {
  uint x = __builtin_bit_cast(uint, f);
  uint r = x + 0x7FFFu + ((x >> 16) & 1u);
  return (ushort)(r >> 16);
}
__device__ __forceinline__ float bf2f(ushort u) {
  uint x = (uint)u << 16;
  return __builtin_bit_cast(float, x);
}
__device__ __forceinline__ void gload16(const void* g, void* l) {
  __builtin_amdgcn_global_load_lds(
      (const __attribute__((address_space(1))) void*)g,
      (__attribute__((address_space(3))) void*)l, 16, 0, 0);
}

// ---------------- merged weight pack kernel ----------------
struct PackArgs {
  const float *W0, *W1r, *W1i, *W2r, *W2i;
  const float *s0, *s1, *s2, *s3, *s4, *s5, *we, *t0, *t1, *t2, *p0;
  ushort *B0, *B1, *B2;
  ushort *d0, *d1, *d2, *d3, *d4, *d5, *dwe, *dtt, *dp0;
};
__global__ __launch_bounds__(256) void k_pack(PackArgs p) {
  int bid = blockIdx.x;
  if (bid < 2160) {
    int idx = bid * 256 + threadIdx.x;
    if (idx >= 160 * 3456) return;
    int o = idx / 3456, kf = idx - o * 3456;
    int k = kf / 384, f = kf - k * 384;
    float v = (f < 336) ? p.W0[k * 53760 + f * 160 + o] : 0.f;
    p.B0[idx] = f2bf(v);
  } else if (bid < 3240) {
    int idx = (bid - 2160) * 256 + threadIdx.x;
    if (idx >= 96 * 2880) return;
    int c = idx / 2880, kf = idx - c * 2880;
    int k = kf / 320, f = kf - k * 320;
    float v = 0.f;
    if (f < 288) {
      if (c < 48) v = (f < 144) ? p.W1r[k * 6912 + f * 48 + c] : -p.W1i[k * 6912 + (f - 144) * 48 + c];
      else        v = (f < 144) ? p.W1i[k * 6912 + f * 48 + (c - 48)] : p.W1r[k * 6912 + (f - 144) * 48 + (c - 48)];
    }
    p.B1[idx] = f2bf(v);
  } else if (bid < 3384) {
    int idx = (bid - 3240) * 256 + threadIdx.x;
    if (idx >= 32 * 1152) return;
    int c = idx / 1152, kf = idx - c * 1152;
    int k = kf / 128, f = kf - k * 128;
    float v = 0.f;
    if (f < 96) {
      if (c < 16) v = (f < 48) ? p.W2r[k * 768 + f * 16 + c] : -p.W2i[k * 768 + (f - 48) * 16 + c];
      else        v = (f < 48) ? p.W2i[k * 768 + f * 16 + (c - 16)] : p.W2r[k * 768 + (f - 48) * 16 + (c - 16)];
    }
    p.B2[idx] = f2bf(v);
  } else {
    int idx = (bid - 3384) * 256 + threadIdx.x;
    if (idx < 24576) {
      int n = idx / 192, k = idx - n * 192;
      p.d0[idx] = f2bf(p.s0[k * 128 + n]);
    } else if (idx < 40960) {
      int q = idx - 24576; int n = q >> 7, k = q & 127;
      p.d1[q] = f2bf(p.s1[k * 128 + n]);
    } else if (idx < 57344) {
      int q = idx - 40960; int n = q >> 7, k = q & 127;
      p.d2[q] = f2bf(p.s2[k * 128 + n]);
    } else if (idx < 90112) {
      int q = idx - 57344; int n = q / 256, k = q - n * 256;
      p.d3[q] = f2bf(p.s3[k * 128 + n]);
    } else if (idx < 106496) {
      int q = idx - 90112; int n = q >> 7, k = q & 127;
      p.d4[q] = f2bf(p.s4[k * 128 + n]);
    } else if (idx < 122880) {
      int q = idx - 106496; int n = q >> 7, k = q & 127;
      p.d5[q] = f2bf(p.s5[k * 128 + n]);
    } else if (idx < 139264) {
      int q = idx - 122880; int n = q >> 7, k = q & 127;
      p.dwe[q] = f2bf((n < 112) ? p.we[k * 112 + n] : 0.f);
    } else if (idx < 155648) {
      int q = idx - 139264; int o = q >> 7, h = q & 127;
      float v = 0.f;
      if (o < 64) v = p.t0[o * 128 + h];
      else if (o < 96) v = p.t1[(o - 64) * 128 + h];
      else if (o < 112) v = p.t2[(o - 96) * 128 + h];
      p.dtt[q] = f2bf(v);
    } else if (idx < 159744) {
      int q = idx - 155648; int n = q >> 6, k = q & 63;
      p.dp0[q] = f2bf(p.p0[k * 64 + n]);
    }
  }
}

// ---------------- prep: gather + Wigner rotate + softmax gates (wave-per-edge) ----------------
__global__ __launch_bounds__(256) void k_prep(
    const float* __restrict__ node_f, const float* __restrict__ edge_f,
    const float* __restrict__ D1g, const float* __restrict__ D2g,
    const float* __restrict__ mg_g, const float* __restrict__ Wg,
    const float* __restrict__ latg, const float* __restrict__ eohg,
    const int* __restrict__ eidx, const int* __restrict__ act,
    ushort* __restrict__ f_all, float* __restrict__ gf_out,
    ushort* __restrict__ lat_bf, ushort* __restrict__ mlp2_in) {
  __shared__ float sh[4][1244];
  const int w = threadIdx.x >> 6, lane = threadIdx.x & 63;
  const int e = blockIdx.x * 4 + w;
  float* s = sh[w];
  float* s_nc = s;
  float* s_ef = s + 240;
  float* s_nn = s + 480;
  float* s_d1 = s + 720;
  float* s_d2 = s + 729;
  float* s_mg = s + 754;
  float* s_lg = s + 818;
  ushort* row = (ushort*)(s + 828);
  const int ae = act[e];
  const int ec = eidx[ae], en = eidx[EDGES + ae];
  if (lane < 60) {
    ((float4v*)s_nc)[lane] = ((const float4v*)(node_f + (size_t)ec * 240))[lane];
    ((float4v*)s_ef)[lane] = ((const float4v*)(edge_f + (size_t)e * 240))[lane];
    ((float4v*)s_nn)[lane] = ((const float4v*)(node_f + (size_t)en * 240))[lane];
  }
  if (lane < 9)  s_d1[lane] = D1g[e * 9 + lane];
  if (lane < 25) s_d2[lane] = D2g[e * 25 + lane];
  s_mg[lane] = mg_g[e * 64 + lane];
  {
    const float* lp = latg + (size_t)ae * 128;
    float a0 = lp[2 * lane], a1 = lp[2 * lane + 1];
    ((uint*)lat_bf)[(size_t)e * 64 + lane] = (uint)f2bf(a0) | ((uint)f2bf(a1) << 16);
    const float* ep = eohg + (size_t)e * 128;
    a0 = ep[2 * lane]; a1 = ep[2 * lane + 1];
    ((uint*)mlp2_in)[(size_t)e * 128 + 64 + lane] = (uint)f2bf(a0) | ((uint)f2bf(a1) << 16);
  }
  {
    int k = lane & 7, hg = lane >> 3;
    float a = 0.f;
#pragma unroll
    for (int h = 0; h < 8; ++h) a += s_mg[hg * 8 + h] * Wg[(hg * 8 + h) * 8 + k];
    a += __shfl_xor(a, 8);
    a += __shfl_xor(a, 16);
    a += __shfl_xor(a, 32);
    if (lane < 8) s_lg[lane] = a;
  }
  if (lane < 12) {
    float m = s_lg[0];
    for (int j = 1; j < 8; ++j) m = fmaxf(m, s_lg[j]);
    float den = 0.f;
    for (int j = 0; j < 8; ++j) den += __expf(s_lg[j] - m);
    float v = 0.f;
    if (lane < 8) v = __expf(s_lg[lane] - m) / den;
    else if (lane == 8) v = 1.f;
    gf_out[e * 12 + lane] = v;
  }
  row[lane]       = f2bf(s_nc[lane]);
  row[64 + lane]  = f2bf(s_ef[lane]);
  row[128 + lane] = f2bf(s_nn[lane]);
  if (lane < 48) row[336 + lane] = 0;
  if (lane < 32) { row[672 + lane] = 0; row[800 + lane] = 0; }
#pragma unroll
  for (int it = 0; it < 5; ++it) {
    int q = lane + it * 64;
    if (q < 288) {
      int i = q / 96, c = q - i * 96;
      const float* src = (c < 32) ? s_nc : (c < 64) ? s_ef : s_nn;
      int base = 64 + (c & 31) * 3;
      float v = s_d1[i * 3] * src[base] + s_d1[i * 3 + 1] * src[base + 1] + s_d1[i * 3 + 2] * src[base + 2];
      int dst = (i == 0) ? 528 : (i == 1) ? 192 : 384;
      row[dst + c] = f2bf(v);
    }
  }
#pragma unroll
  for (int it = 0; it < 4; ++it) {
    int q = lane + it * 64;
    if (q < 240) {
      int i = q / 48, c = q - i * 48;
      const float* src = (c < 16) ? s_nc : (c < 32) ? s_ef : s_nn;
      int base = 160 + (c & 15) * 5;
      float v = s_d2[i * 5] * src[base] + s_d2[i * 5 + 1] * src[base + 1] +
                s_d2[i * 5 + 2] * src[base + 2] + s_d2[i * 5 + 3] * src[base + 3] +
                s_d2[i * 5 + 4] * src[base + 4];
      int dst = (i == 0) ? 752 : (i == 1) ? 624 : (i == 2) ? 288 : (i == 3) ? 480 : 704;
      row[dst + c] = f2bf(v);
    }
  }
  const uintx4* row4 = (const uintx4*)row;
  uintx4* dst4 = (uintx4*)(f_all + (size_t)e * 832);
#pragma unroll
  for (int it = 0; it < 2; ++it) {
    int q = lane + it * 64;
    if (q < 104) dst4[q] = row4[q];
  }
}

// ------- bf16 MFMA GEMM body (device) -------
// NGRP>1: A-fragments cached in registers; LDS holds B only.
// NGRP==1: classic A+B double-buffered DMA staging.
template <int WAVES, int BM, int KZP, int SPG2, int NGRP, int NCOL, int FOFF, int ASTRIDE,
          bool HASBIAS, int EPI>
__device__ __forceinline__ void gemm_dev(
    int bid, char* sm,
    const ushort* __restrict__ A, const ushort* __restrict__ Bt,
    const float* __restrict__ gf, const float* __restrict__ bias,
    ushort* __restrict__ outb, int ob_stride, int ob_off,
    ushort* __restrict__ outb2) {
  constexpr int T = WAVES * 64;
  constexpr int WRS = WAVES / 2;
  constexpr int RPW = BM / WRS;
  constexpr int MI = RPW / 16;
  constexpr int NFW = NCOL / 32;
  constexpr int A_BYTES = BM * 128;
  constexpr int B_BYTES = NCOL * 128;
  constexpr int NT2 = KZP / 64;
  constexpr int AI = (BM * 8) / T;
  constexpr int NB = NCOL * 8;
  constexpr int BI = (NB + T - 1) / T;
  static_assert(NCOL % 32 == 0 && KZP % 64 == 0 && RPW % 16 == 0 && (BM * 8) % T == 0, "geom");
  const int tid = threadIdx.x;
  const int lane = tid & 63, wid = tid >> 6;
  const int wr = wid >> 1, wc = wid & 1;
  const int g16 = lane >> 4;
  const int lane15 = lane & 15;
  const int e0 = bid * BM;
  const f32x4 vzero = {0.f, 0.f, 0.f, 0.f};

  const char* bSrc[BI];
#pragma unroll
  for (int it = 0; it < BI; ++it) {
    int q = tid + it * T;
    if (q < NB) {
      int c = q >> 3, ch = (q & 7) ^ (c & 7);
      bSrc[it] = (const char*)(Bt + (size_t)c * KZP) + ch * 16;
    } else bSrc[it] = nullptr;
  }

  f32x4 accS[MI][NFW];
#pragma unroll
  for (int mi = 0; mi < MI; ++mi)
#pragma unroll
    for (int n = 0; n < NFW; ++n) accS[mi][n] = vzero;

  if constexpr (NGRP > 1) {
    char* b_lds = sm;
    f32x4 accC[MI][NFW];
#pragma unroll
    for (int mi = 0; mi < MI; ++mi)
#pragma unroll
      for (int n = 0; n < NFW; ++n) accC[mi][n] = vzero;

    float gfr[MI][4];
    auto gf_pref = [&](int gx) {
#pragma unroll
      for (int mi = 0; mi < MI; ++mi)
#pragma unroll
        for (int j = 0; j < 4; ++j)
          gfr[mi][j] = gf[(size_t)(e0 + wr * RPW + mi * 16 + g16 * 4 + j) * 12 + gx];
    };
    gf_pref(0);

    bf16x8 afr[SPG2][MI][2];
#pragma unroll
    for (int wi = 0; wi < SPG2; ++wi)
#pragma unroll
      for (int mi = 0; mi < MI; ++mi)
#pragma unroll
        for (int s = 0; s < 2; ++s)
          afr[wi][mi][s] = *(const bf16x8*)(
              A + (size_t)(e0 + wr * RPW + mi * 16 + lane15) * ASTRIDE + FOFF +
              wi * 64 + s * 32 + g16 * 8);

    auto stageB = [&](int t2, int buf) {
#pragma unroll
      for (int it = 0; it < BI; ++it) {
        int q = tid + it * T;
        if (q < NB)
          gload16(bSrc[it] + (size_t)t2 * 128, b_lds + buf * B_BYTES + (tid - lane + it * T) * 16);
      }
    };

    stageB(0, 0);
    __syncthreads();
    int cur = 0;
    for (int g = 0; g < NGRP; ++g) {
#pragma unroll
      for (int wi = 0; wi < SPG2; ++wi) {
        int t2 = g * SPG2 + wi;
        if (t2 + 1 < NT2) stageB(t2 + 1, cur ^ 1);
        const char* bL = b_lds + cur * B_BYTES;
#pragma unroll
        for (int s = 0; s < 2; ++s) {
#pragma unroll
          for (int n = 0; n < NFW; ++n) {
            int cB = (wc * NFW + n) * 16 + lane15;
            int slot = (s * 4 + g16) ^ (cB & 7);
            bf16x8 b = *(const bf16x8*)(bL + cB * 128 + slot * 16);
#pragma unroll
            for (int mi = 0; mi < MI; ++mi)
              accC[mi][n] = __builtin_amdgcn_mfma_f32_16x16x32_bf16(afr[wi][mi][s], b, accC[mi][n], 0, 0, 0);
          }
        }
        if (wi == SPG2 - 1) {
#pragma unroll
          for (int mi = 0; mi < MI; ++mi)
#pragma unroll
            for (int n = 0; n < NFW; ++n) {
#pragma unroll
              for (int j = 0; j < 4; ++j) accS[mi][n][j] += gfr[mi][j] * accC[mi][n][j];
              accC[mi][n] = vzero;
            }
          if (g + 1 < NGRP) gf_pref(g + 1);
        }
        __syncthreads();
        cur ^= 1;
      }
    }
  } else {
    char* a_lds = sm;
    char* b_lds = sm + 2 * A_BYTES;
    const char* aSrc[AI];
#pragma unroll
    for (int it = 0; it < AI; ++it) {
      int q = tid + it * T;
      int r = q >> 3, ch = (q & 7) ^ (r & 7);
      aSrc[it] = (const char*)(A + (size_t)(e0 + r) * ASTRIDE + FOFF) + ch * 16;
    }
    auto stage = [&](int t2, int buf) {
#pragma unroll
      for (int it = 0; it < AI; ++it)
        gload16(aSrc[it] + t2 * 128, a_lds + buf * A_BYTES + (tid - lane + it * T) * 16);
#pragma unroll
      for (int it = 0; it < BI; ++it) {
        int q = tid + it * T;
        if (q < NB)
          gload16(bSrc[it] + t2 * 128, b_lds + buf * B_BYTES + (tid - lane + it * T) * 16);
      }
    };
    stage(0, 0);
    __syncthreads();
    int cur = 0;
    for (int t2 = 0; t2 < NT2; ++t2) {
      if (t2 + 1 < NT2) stage(t2 + 1, cur ^ 1);
      const char* aL = a_lds + cur * A_BYTES;
      const char* bL = b_lds + cur * B_BYTES;
#pragma unroll
      for (int s = 0; s < 2; ++s) {
        bf16x8 a[MI];
#pragma unroll
        for (int mi = 0; mi < MI; ++mi) {
          int rA = wr * RPW + mi * 16 + lane15;
          int slot = (s * 4 + g16) ^ (rA & 7);
          a[mi] = *(const bf16x8*)(aL + rA * 128 + slot * 16);
        }
#pragma unroll
        for (int n = 0; n < NFW; ++n) {
          int cB = (wc * NFW + n) * 16 + lane15;
          int slot = (s * 4 + g16) ^ (cB & 7);
          bf16x8 b = *(const bf16x8*)(bL + cB * 128 + slot * 16);
#pragma unroll
          for (int mi = 0; mi < MI; ++mi)
            accS[mi][n] = __builtin_amdgcn_mfma_f32_16x16x32_bf16(a[mi], b, accS[mi][n], 0, 0, 0);
        }
      }
      __syncthreads();
      cur ^= 1;
    }
  }

#pragma unroll
  for (int mi = 0; mi < MI; ++mi) {
    const int row0 = wr * RPW + mi * 16 + g16 * 4;
#pragma unroll
    for (int n = 0; n < NFW; ++n) {
      const int c = (wc * NFW + n) * 16 + lane15;
      float bv = 0.f;
      if constexpr (HASBIAS) bv = bias[c];
#pragma unroll
      for (int j = 0; j < 4; ++j) {
        float v = accS[mi][n][j] + bv;
        const int er = e0 + row0 + j;
        if constexpr (EPI == 1) v = v / (1.f + __expf(-v));
        outb[(size_t)er * ob_stride + ob_off + c] = f2bf(v);
        if constexpr (EPI == 2) {
          if ((wc * NFW + n) * 16 < 64)
            outb2[(size_t)er * 256 + c] = f2bf(v / (1.f + __expf(-v)));
        }
      }
    }
  }
}

// ---- merged MoE GEMMs: one launch, 512-thread blocks (R17 proven config) ----
struct MoeArgs {
  const ushort *f_all, *B0t, *B1t, *B2t;
  const float* gfb;
  ushort *moeout, *m2in;
};
__global__ __launch_bounds__(512) void k_moe(MoeArgs a) {
  __shared__ char sm[2 * 160 * 128 + 16];  // max B double-buffer (moe0)
  int bid = blockIdx.x;
  if (bid < 512) {
    gemm_dev<8, 128, 3456, 6, 9, 160, 0, 832, false, 2>(
        bid, sm, a.f_all, a.B0t, a.gfb, nullptr, a.moeout, 288, 0, a.m2in);
  } else if (bid < 1024) {
    gemm_dev<8, 128, 2880, 5, 9, 96, 384, 832, false, 0>(
        bid - 512, sm, a.f_all, a.B1t, a.gfb, nullptr, a.moeout, 288, 160, nullptr);
  } else {
    gemm_dev<8, 128, 1152, 2, 9, 32, 704, 832, false, 0>(
        bid - 1024, sm, a.f_all, a.B2t, a.gfb, nullptr, a.moeout, 288, 256, nullptr);
  }
}

// ---- merged small GEMMs ----
struct Small3Args {
  const ushort *latbf, *Wet, *m2in, *Ttb, *P0t;
  const float* b0;
  ushort *wbuf, *tbuf, *m1in;
};
__global__ __launch_bounds__(256) void k_small3(Small3Args a) {
  __shared__ char sm[49168];
  int bid = blockIdx.x;
  if (bid < 1024) {
    gemm_dev<4, 64, 128, 1, 1, 128, 0, 128, false, 0>(
        bid, sm, a.latbf, a.Wet, nullptr, nullptr, a.wbuf, 128, 0, nullptr);
  } else if (bid < 2048) {
    gemm_dev<4, 64, 128, 1, 1, 128, 128, 256, false, 0>(
        bid - 1024, sm, a.m2in, a.Ttb, nullptr, nullptr, a.tbuf, 128, 0, nullptr);
  } else {
    gemm_dev<4, 64, 64, 1, 1, 64, 0, 256, true, 0>(
        bid - 2048, sm, a.m2in, a.P0t, nullptr, a.b0, a.m1in, 192, 128, nullptr);
  }
}

// ---------------- fused 6-layer MLP: 32 edges/block, X in LDS, W double-buffered ----------
struct MlpArgs {
  const ushort *m1in, *m2in, *Wt1, *Wt2, *Wt3, *Wt4, *Wt5, *Wt6;
  const float *b1, *b2, *b3, *b4, *b5, *b6;
  const int* act;
  const float *cutg, *latg;
  float* out_lat;
};
__global__ __launch_bounds__(256) void k_mlp(MlpArgs A) {
  __shared__ char sm[61440];
  char* Xa = sm;
  char* Xb = sm + 12288;
  char* Xe = sm + 20480;
  char* W0 = sm + 28672;
  char* W1 = sm + 45056;
  const int tid = threadIdx.x;
  const int lane = tid & 63, w = tid >> 6;
  const int wr = w >> 1, wc = w & 1;
  const int lane15 = lane & 15, g16 = lane >> 4;
  const int e32 = blockIdx.x * 32;
  const f32x4 vzero = {0.f, 0.f, 0.f, 0.f};

  auto stage_w = [&](const ushort* Wt, int K2, int t2, char* dst) {
#pragma unroll
    for (int it = 0; it < 4; ++it) {
      int q = tid + it * 256;
      int c = q >> 3, ch = (q & 7) ^ (c & 7);
      gload16((const char*)Wt + (size_t)c * K2 + t2 * 128 + ch * 16,
              dst + (w + it * 4) * 1024);
    }
  };
  {
#pragma unroll
    for (int it = 0; it < 3; ++it) {
      int q = tid + it * 256;
      int r = q / 24, c24 = q - r * 24;
      int t2 = c24 >> 3, ch = (c24 & 7) ^ (r & 7);
      gload16((const char*)A.m1in + (size_t)(e32 + r) * 384 + t2 * 128 + ch * 16,
              Xa + (w + it * 4) * 1024);
    }
#pragma unroll
    for (int it = 0; it < 2; ++it) {
      int q = tid + it * 256;
      int r = q >> 4, c16 = q & 15;
      int t2 = c16 >> 3, ch = (c16 & 7) ^ (r & 7);
      gload16((const char*)A.m2in + (size_t)(e32 + r) * 512 + 256 + t2 * 128 + ch * 16,
              Xe + (w + it * 4) * 1024);
    }
  }
  stage_w(A.Wt1, 384, 0, W0);
  __syncthreads();

  f32x4 acc[4];
#pragma unroll
  for (int n = 0; n < 4; ++n) acc[n] = vzero;

  auto compute = [&](const char* xin, int xstride, int t2loc, const char* wl) {
#pragma unroll
    for (int s = 0; s < 2; ++s) {
      int row = wr * 16 + lane15;
      bf16x8 a = *(const bf16x8*)(xin + row * xstride + t2loc * 128 + (((s * 4 + g16) ^ (row & 7)) << 4));
#pragma unroll
      for (int n = 0; n < 4; ++n) {
        int cB = wc * 64 + n * 16 + lane15;
        bf16x8 b = *(const bf16x8*)(wl + cB * 128 + (((s * 4 + g16) ^ (cB & 7)) << 4));
        acc[n] = __builtin_amdgcn_mfma_f32_16x16x32_bf16(a, b, acc[n], 0, 0, 0);
      }
    }
  };
  auto epi_x = [&](const float* bias, char* xout, int xstride, bool dosilu) {
#pragma unroll
    for (int n = 0; n < 4; ++n) {
      int c = wc * 64 + n * 16 + lane15;
      float bv = bias[c];
      int ch = (n * 16 + lane15) >> 3;
#pragma unroll
      for (int j = 0; j < 4; ++j) {
        int row = wr * 16 + g16 * 4 + j;
        float v = acc[n][j] + bv;
        if (dosilu) v = v / (1.f + __expf(-v));
        *(ushort*)(xout + row * xstride + wc * 128 + ((ch ^ (row & 7)) << 4) + ((lane15 & 7) << 1)) = f2bf(v);
      }
      acc[n] = vzero;
    }
  };

  stage_w(A.Wt1, 384, 1, W1); compute(Xa, 384, 0, W0); __syncthreads();
  stage_w(A.Wt1, 384, 2, W0); compute(Xa, 384, 1, W1); __syncthreads();
  stage_w(A.Wt2, 256, 0, W1); compute(Xa, 384, 2, W0); epi_x(A.b1, Xb, 256, true); __syncthreads();
  stage_w(A.Wt2, 256, 1, W0); compute(Xb, 256, 0, W1); __syncthreads();
  stage_w(A.Wt3, 256, 0, W1); compute(Xb, 256, 1, W0); epi_x(A.b2, Xa, 384, true); __syncthreads();
  stage_w(A.Wt3, 256, 1, W0); compute(Xa, 384, 0, W1); __syncthreads();
  stage_w(A.Wt4, 512, 0, W1); compute(Xa, 384, 1, W0); epi_x(A.b3, Xb, 256, false); __syncthreads();
  stage_w(A.Wt4, 512, 1, W0); compute(Xb, 256, 0, W1); __syncthreads();
  stage_w(A.Wt4, 512, 2, W1); compute(Xb, 256, 1, W0); __syncthreads();
  stage_w(A.Wt4, 512, 3, W0); compute(Xe, 256, 0, W1); __syncthreads();
  stage_w(A.Wt5, 256, 0, W1); compute(Xe, 256, 1, W0); epi_x(A.b4, Xa, 384, true); __syncthreads();
  stage_w(A.Wt5, 256, 1, W0); compute(Xa, 384, 0, W1); __syncthreads();
  stage_w(A.Wt6, 256, 0, W1); compute(Xa, 384, 1, W0); epi_x(A.b5, Xb, 256, true); __syncthreads();
  stage_w(A.Wt6, 256, 1, W0); compute(Xb, 256, 0, W1); __syncthreads();
  compute(Xb, 256, 1, W0);
#pragma unroll
  for (int n = 0; n < 4; ++n) {
    int c = wc * 64 + n * 16 + lane15;
    float bv = A.b6[c];
#pragma unroll
    for (int j = 0; j < 4; ++j) {
      int row = wr * 16 + g16 * 4 + j;
      int er = e32 + row;
      int ae = A.act[er];
      float v = acc[n][j] + bv;
      A.out_lat[(size_t)ae * 128 + c] = C_NEW * A.cutg[ae] * v + C_OLD * A.latg[(size_t)ae * 128 + c];
    }
  }
}

// ------ post-MoE + final combine: wave-per-edge, 8 edges/block; P-mixes via 3 MFMAs ------
__global__ __launch_bounds__(512) void k_postf(
    const ushort* __restrict__ moeout,
    const float* __restrict__ D1g, const float* __restrict__ D2g,
    const float* __restrict__ latg, const int* __restrict__ act,
    const float* __restrict__ P1, const float* __restrict__ P2,
    const ushort* __restrict__ wbuf, const float* __restrict__ beg,
    const float* __restrict__ lng, const float* __restrict__ lnb,
    const ushort* __restrict__ tbufp, const float* __restrict__ efg,
    ushort* __restrict__ m1in, float* __restrict__ out_edge) {
  __shared__ float SM[1136 + 8 * 920];
  ushort* Btab = (ushort*)SM;
  float* be_s = SM + 768;
  float* lng_s = SM + 880;
  float* lnb_s = SM + 1008;
  const int t = threadIdx.x;
  const int w = t >> 6, lane = t & 63;
  float* Wp = SM + 1136 + w * 920;
  float* o   = Wp;
  float* row = Wp + 224;
  float* sg  = Wp + 464;
  float* d1  = Wp + 512;
  float* d2  = Wp + 524;
  ushort* wvh = (ushort*)(Wp + 552);
  ushort* tvh = (ushort*)(Wp + 608);
  ushort* tile = (ushort*)(Wp + 664);
  const int e = blockIdx.x * 8 + w;
  const int ae = act[e];
  const f32x4 vzero = {0.f, 0.f, 0.f, 0.f};

  float ef[4];
  ef[0] = efg[(size_t)e * 240 + lane];
  ef[1] = efg[(size_t)e * 240 + 64 + lane];
  ef[2] = efg[(size_t)e * 240 + 128 + lane];
  ef[3] = (lane < 48) ? efg[(size_t)e * 240 + 192 + lane] : 0.f;
  float2v ll = ((const float2v*)(latg + (size_t)ae * 128))[lane];

  if (lane < 28) {
    uintx4 raw = *(const uintx4*)(moeout + (size_t)e * 288 + 64 + lane * 8);
    float* dst = o + lane * 8;
#pragma unroll
    for (int j = 0; j < 4; ++j) {
      uint u = raw[j];
      dst[2 * j] = bf2f((ushort)(u & 0xFFFF));
      dst[2 * j + 1] = bf2f((ushort)(u >> 16));
    }
  }
  if (lane < 14) {
    *(uintx4*)((char*)wvh + lane * 16) = *(const uintx4*)(wbuf + (size_t)e * 128 + lane * 8);
    *(uintx4*)((char*)tvh + lane * 16) = *(const uintx4*)(tbufp + (size_t)e * 128 + lane * 8);
  }
  if (lane < 8) {
    uintx4 raw = *(const uintx4*)(m1in + (size_t)e * 192 + 128 + lane * 8);
    float* dst = row + lane * 8;
#pragma unroll
    for (int j = 0; j < 4; ++j) {
      uint u = raw[j];
      dst[2 * j] = bf2f((ushort)(u & 0xFFFF));
      dst[2 * j + 1] = bf2f((ushort)(u >> 16));
    }
  }
  if (lane < 9)  d1[lane] = D1g[(size_t)e * 9 + lane];
  if (lane < 25) d2[lane] = D2g[(size_t)e * 25 + lane];
  if (lane < 48) sg[lane] = 1.f / (1.f + __expf(-o[lane]));

#pragma unroll
  for (int i = 0; i < 3; ++i) {
    int q = t + i * 512;
    int tbl = q >> 9, idx = q & 511;
    int d = idx >> 5, c = idx & 31;
    float v;
    if (tbl == 0) v = P1[c * 32 + d];
    else if (tbl == 1) v = P1[c * 32 + 16 + d];
    else v = (c < 16) ? P2[c * 16 + d] : 0.f;
    Btab[tbl * 512 + d * 32 + (((c >> 3) ^ (d & 3)) << 3) + (c & 7)] = f2bf(v);
  }
  if (t < 368) {
    if (t < 112) be_s[t] = beg[t];
    else if (t < 240) lng_s[t - 112] = lng[t - 112];
    else lnb_s[t - 240] = lnb[t - 240];
  }

  float sum = ll[0] + ll[1];
  float sq = ll[0] * ll[0] + ll[1] * ll[1];
#pragma unroll
  for (int m = 32; m > 0; m >>= 1) {
    sum += __shfl_xor(sum, m);
    sq += __shfl_xor(sq, m);
  }
  const float mu = sum * (1.f / 128.f);
  const float rs = rsqrtf(sq * (1.f / 128.f) - mu * mu + 1e-5f);

  __syncthreads();

  {
    int i = 2 * lane;
    float l0 = (ll[0] - mu) * rs * lng_s[i] + lnb_s[i];
    float l1 = (ll[1] - mu) * rs * lng_s[i + 1] + lnb_s[i + 1];
    ((uint*)m1in)[(size_t)e * 96 + lane] = (uint)f2bf(l0) | ((uint)f2bf(l1) << 16);
  }
#pragma unroll
  for (int rr = 0; rr < 2; ++rr) {
    int r = lane + rr * 64;
    if (r < 96) {
      int m = r >> 5, c = r & 31;
      float v = d1[m] * o[144 + c] + d1[3 + m] * o[48 + c] + d1[6 + m] * o[96 + c];
      tile[m * 32 + (((c >> 3) ^ (m & 3)) << 3) + (c & 7)] = f2bf(v * sg[c]);
    }
  }
#pragma unroll
  for (int rr = 0; rr < 3; ++rr) {
    int r = lane + rr * 64;
    if (r < 160) {
      int rw = 3 + (r >> 5), c = r & 31;
      ushort hv = 0;
      if (c < 16) {
        int m = rw - 3;
        float v = d2[m] * o[208 + c] + d2[5 + m] * o[176 + c] + d2[10 + m] * o[80 + c] +
                  d2[15 + m] * o[128 + c] + d2[20 + m] * o[192 + c];
        hv = f2bf(v * sg[32 + c]);
      }
      tile[rw * 32 + (((c >> 3) ^ (rw & 3)) << 3) + (c & 7)] = hv;
    }
  }
  {
    const int r15 = lane & 15, g = lane >> 4;
    const int fslot = (g ^ (r15 & 3)) << 3;
    bf16x8 afr = *(const bf16x8*)(tile + r15 * 32 + fslot);
    bf16x8 b1a = *(const bf16x8*)(Btab + r15 * 32 + fslot);
    bf16x8 b1b = *(const bf16x8*)(Btab + 512 + r15 * 32 + fslot);
    bf16x8 b2p = *(const bf16x8*)(Btab + 1024 + r15 * 32 + fslot);
    f32x4 v1a = __builtin_amdgcn_mfma_f32_16x16x32_bf16(afr, b1a, vzero, 0, 0, 0);
    f32x4 v1b = __builtin_amdgcn_mfma_f32_16x16x32_bf16(afr, b1b, vzero, 0, 0, 0);
    f32x4 v2r = __builtin_amdgcn_mfma_f32_16x16x32_bf16(afr, b2p, vzero, 0, 0, 0);
    if (g == 0) {
      float s1 = bf2f(wvh[64 + r15]) + be_s[64 + r15];
      row[64 + r15 * 3 + 0] = v1a[0] * s1;
      row[64 + r15 * 3 + 1] = v1a[1] * s1;
      row[64 + r15 * 3 + 2] = v1a[2] * s1;
      float s2 = bf2f(wvh[80 + r15]) + be_s[80 + r15];
      row[64 + (16 + r15) * 3 + 0] = v1b[0] * s2;
      row[64 + (16 + r15) * 3 + 1] = v1b[1] * s2;
      row[64 + (16 + r15) * 3 + 2] = v1b[2] * s2;
      float s3 = bf2f(wvh[96 + r15]) + be_s[96 + r15];
      row[160 + r15 * 5 + 0] = v2r[3] * s3;
    } else if (g == 1) {
      float s3 = bf2f(wvh[96 + r15]) + be_s[96 + r15];
      row[160 + r15 * 5 + 1] = v2r[0] * s3;
      row[160 + r15 * 5 + 2] = v2r[1] * s3;
      row[160 + r15 * 5 + 3] = v2r[2] * s3;
      row[160 + r15 * 5 + 4] = v2r[3] * s3;
    }
  }
  row[lane] = row[lane] * (bf2f(wvh[lane]) + be_s[lane]);
#pragma unroll
  for (int r = 0; r < 4; ++r) {
    int d = lane + r * 64;
    if (r < 3 || lane < 48) {
      float v = C_OLD * ef[r] + C_NEW * row[d];
      int ti = (d < 64) ? d : (d < 160) ? 64 + (d - 64) / 3 : 96 + (d - 160) / 5;
      float f = bf2f(tvh[ti]) * T_SCALE;
      out_edge[(size_t)e * 240 + d] = v * (1.f + f);
    }
  }
}

extern "C" void kernel_launch(void* const* d_in, const int* in_sizes, int n_in,
                              void* d_out, int out_size, void* d_ws, size_t ws_size,
                              hipStream_t stream) {
  const float* latents = (const float*)d_in[0];
  const float* node_f  = (const float*)d_in[1];
  const float* edge_f  = (const float*)d_in[3];
  const float* cutoff  = (const float*)d_in[5];
  const float* eoh     = (const float*)d_in[6];
  const float* D1      = (const float*)d_in[7];
  const float* D2      = (const float*)d_in[8];
  const float* mg      = (const float*)d_in[9];
  const int*   eidx    = (const int*)d_in[10];
  const int*   act     = (const int*)d_in[11];
  const float* Wg      = (const float*)d_in[12];
  const float* W0      = (const float*)d_in[13];
  const float* W1r     = (const float*)d_in[14];
  const float* W1i     = (const float*)d_in[15];
  const float* W2r     = (const float*)d_in[16];
  const float* W2i     = (const float*)d_in[17];
  const float* P0      = (const float*)d_in[18];
  const float* b0      = (const float*)d_in[19];
  const float* P1      = (const float*)d_in[20];
  const float* P2      = (const float*)d_in[21];
  const float* We      = (const float*)d_in[22];
  const float* be      = (const float*)d_in[23];
  const float* lng     = (const float*)d_in[24];
  const float* lnb     = (const float*)d_in[25];
  const float* M1W0_   = (const float*)d_in[26];
  const float* M1b0_   = (const float*)d_in[27];
  const float* M1W1_   = (const float*)d_in[28];
  const float* M1b1_   = (const float*)d_in[29];
  const float* M1W2_   = (const float*)d_in[30];
  const float* M1b2_   = (const float*)d_in[31];
  const float* M2W0_   = (const float*)d_in[32];
  const float* M2b0_   = (const float*)d_in[33];
  const float* M2W1_   = (const float*)d_in[34];
  const float* M2b1_   = (const float*)d_in[35];
  const float* M2W2_   = (const float*)d_in[36];
  const float* M2b2_   = (const float*)d_in[37];
  const float* T0      = (const float*)d_in[38];
  const float* T1      = (const float*)d_in[39];
  const float* T2      = (const float*)d_in[40];

  float* out_edge = (float*)d_out;
  float* out_lat  = out_edge + (size_t)EDGES * 240;
  float* out_d1   = out_lat + (size_t)EDGES * 128;
  float* out_d2   = out_d1 + (size_t)EDGES * 9;

  char* ws = (char*)d_ws;
  size_t off = 0;
  auto alloc = [&](size_t bytes) -> char* {
    char* p = ws + off;
    off += (bytes + 255) & ~size_t(255);
    return p;
  };
  ushort* f_all  = (ushort*)alloc((size_t)EDGES * 832 * 2);
  float*  gfb    = (float*) alloc((size_t)EDGES * 12 * 4);
  ushort* moeout = (ushort*)alloc((size_t)EDGES * 288 * 2);
  ushort* m2in   = (ushort*)alloc((size_t)EDGES * 256 * 2);
  ushort* latbf  = (ushort*)alloc((size_t)EDGES * 128 * 2);
  ushort* wbuf   = (ushort*)alloc((size_t)EDGES * 128 * 2);
  ushort* B0t    = (ushort*)alloc(160 * 3456 * 2);
  ushort* B1t    = (ushort*)alloc(96 * 2880 * 2);
  ushort* B2t    = (ushort*)alloc(32 * 1152 * 2);
  ushort* Wt1    = (ushort*)alloc(128 * 192 * 2);
  ushort* Wt2    = (ushort*)alloc(128 * 128 * 2);
  ushort* Wt3    = (ushort*)alloc(128 * 128 * 2);
  ushort* Wt4    = (ushort*)alloc(128 * 256 * 2);
  ushort* Wt5    = (ushort*)alloc(128 * 128 * 2);
  ushort* Wt6    = (ushort*)alloc(128 * 128 * 2);
  ushort* Wet    = (ushort*)alloc(128 * 128 * 2);
  ushort* Ttb    = (ushort*)alloc(128 * 128 * 2);
  ushort* P0t    = (ushort*)alloc(64 * 64 * 2);

  ushort* m1in = f_all;   // E*192 overlay (dead after MoE GEMMs)
  ushort* tbuf = latbf;   // reused after We-GEMM

  hipMemcpyAsync(out_d1, (const void*)D1, (size_t)EDGES * 9 * 4, hipMemcpyDeviceToDevice, stream);
  hipMemcpyAsync(out_d2, (const void*)D2, (size_t)EDGES * 25 * 4, hipMemcpyDeviceToDevice, stream);

  if (ws_size < off) return;

  PackArgs pk = {W0, W1r, W1i, W2r, W2i,
                 M1W0_, M1W1_, M1W2_, M2W0_, M2W1_, M2W2_, We, T0, T1, T2, P0,
                 B0t, B1t, B2t,
                 Wt1, Wt2, Wt3, Wt4, Wt5, Wt6, Wet, Ttb, P0t};
  k_pack<<<4008, 256, 0, stream>>>(pk);

  k_prep<<<EDGES / 4, 256, 0, stream>>>(node_f, edge_f, D1, D2, mg, Wg, latents, eoh,
                                        eidx, act, f_all, gfb, latbf, m2in);

  // merged MoE GEMMs: BM=128, 8 waves/block (R17 proven config)
  MoeArgs mo = {f_all, B0t, B1t, B2t, gfb, moeout, m2in};
  k_moe<<<1536, 512, 0, stream>>>(mo);

  // merged small GEMMs: lat@We | eoh@T^T | scs@P0+b0 in one launch
  Small3Args s3 = {latbf, Wet, m2in, Ttb, P0t, b0, wbuf, tbuf, m1in};
  k_small3<<<3072, 256, 0, stream>>>(s3);

  // fused post + final combine (wave-per-edge, 8 edges/block, MFMA P-mixes)
  k_postf<<<EDGES / 8, 512, 0, stream>>>(moeout, D1, D2, latents, act, P1, P2,
                                         wbuf, be, lng, lnb, tbuf, edge_f, m1in, out_edge);

  // fused 6-layer MLP chain (final layer fuses latent update into out_lat)
  MlpArgs ma = {m1in, m2in, Wt1, Wt2, Wt3, Wt4, Wt5, Wt6,
                M1b0_, M1b1_, M1b2_, M2b0_, M2b1_, M2b2_,
                act, cutoff, latents, out_lat};
  k_mlp<<<EDGES / 32, 256, 0, stream>>>(ma);
}

// Round 23
// 420.572 us; speedup vs baseline: 1.0404x; 1.0404x over previous
//
#include <hip/hip_runtime.h>
#include <hip/hip_bf16.h>
#include <stdint.h>

#define EDGES 65536

typedef unsigned int uint;
typedef unsigned short ushort;
using bf16x8 = __attribute__((ext_vector_type(8))) __bf16;
using f32x4  = __attribute__((ext_vector_type(4))) float;
using uintx4 = __attribute__((ext_vector_type(4))) uint;
using float4v = __attribute__((ext_vector_type(4))) float;
using float2v = __attribute__((ext_vector_type(2))) float;

#define C_OLD 0.8944271909999159f
#define C_NEW 0.4472135954999579f
#define T_SCALE 0.08838834764831845f

__device__ __forceinline__ ushort f2bf(float f) {
  uint x = __builtin_bit_cast(uint, f);
  uint r = x + 0x7FFFu + ((x >> 16) & 1u);
  return (ushort)(r >> 16);
}
__device__ __forceinline__ float bf2f(ushort u) {
  uint x = (uint)u << 16;
  return __builtin_bit_cast(float, x);
}
__device__ __forceinline__ void gload16(const void* g, void* l) {
  __builtin_amdgcn_global_load_lds(
      (const __attribute__((address_space(1))) void*)g,
      (__attribute__((address_space(3))) void*)l, 16, 0, 0);
}
// counted-vmcnt wait (immediate must be a literal per variant)
template <int N> __device__ __forceinline__ void wait_vm() {
  if constexpr (N <= 0) asm volatile("s_waitcnt vmcnt(0)" ::: "memory");
  else if constexpr (N == 1) asm volatile("s_waitcnt vmcnt(1)" ::: "memory");
  else if constexpr (N == 2) asm volatile("s_waitcnt vmcnt(2)" ::: "memory");
  else if constexpr (N == 3) asm volatile("s_waitcnt vmcnt(3)" ::: "memory");
  else asm volatile("s_waitcnt vmcnt(4)" ::: "memory");
}

// ---------------- merged weight pack kernel ----------------
struct PackArgs {
  const float *W0, *W1r, *W1i, *W2r, *W2i;
  const float *s0, *s1, *s2, *s3, *s4, *s5, *we, *t0, *t1, *t2, *p0;
  ushort *B0, *B1, *B2;
  ushort *d0, *d1, *d2, *d3, *d4, *d5, *dwe, *dtt, *dp0;
};
__global__ __launch_bounds__(256) void k_pack(PackArgs p) {
  int bid = blockIdx.x;
  if (bid < 2160) {
    int idx = bid * 256 + threadIdx.x;
    if (idx >= 160 * 3456) return;
    int o = idx / 3456, kf = idx - o * 3456;
    int k = kf / 384, f = kf - k * 384;
    float v = (f < 336) ? p.W0[k * 53760 + f * 160 + o] : 0.f;
    p.B0[idx] = f2bf(v);
  } else if (bid < 3240) {
    int idx = (bid - 2160) * 256 + threadIdx.x;
    if (idx >= 96 * 2880) return;
    int c = idx / 2880, kf = idx - c * 2880;
    int k = kf / 320, f = kf - k * 320;
    float v = 0.f;
    if (f < 288) {
      if (c < 48) v = (f < 144) ? p.W1r[k * 6912 + f * 48 + c] : -p.W1i[k * 6912 + (f - 144) * 48 + c];
      else        v = (f < 144) ? p.W1i[k * 6912 + f * 48 + (c - 48)] : p.W1r[k * 6912 + (f - 144) * 48 + (c - 48)];
    }
    p.B1[idx] = f2bf(v);
  } else if (bid < 3384) {
    int idx = (bid - 3240) * 256 + threadIdx.x;
    if (idx >= 32 * 1152) return;
    int c = idx / 1152, kf = idx - c * 1152;
    int k = kf / 128, f = kf - k * 128;
    float v = 0.f;
    if (f < 96) {
      if (c < 16) v = (f < 48) ? p.W2r[k * 768 + f * 16 + c] : -p.W2i[k * 768 + (f - 48) * 16 + c];
      else        v = (f < 48) ? p.W2i[k * 768 + f * 16 + (c - 16)] : p.W2r[k * 768 + (f - 48) * 16 + (c - 16)];
    }
    p.B2[idx] = f2bf(v);
  } else {
    int idx = (bid - 3384) * 256 + threadIdx.x;
    if (idx < 24576) {
      int n = idx / 192, k = idx - n * 192;
      p.d0[idx] = f2bf(p.s0[k * 128 + n]);
    } else if (idx < 40960) {
      int q = idx - 24576; int n = q >> 7, k = q & 127;
      p.d1[q] = f2bf(p.s1[k * 128 + n]);
    } else if (idx < 57344) {
      int q = idx - 40960; int n = q >> 7, k = q & 127;
      p.d2[q] = f2bf(p.s2[k * 128 + n]);
    } else if (idx < 90112) {
      int q = idx - 57344; int n = q / 256, k = q - n * 256;
      p.d3[q] = f2bf(p.s3[k * 128 + n]);
    } else if (idx < 106496) {
      int q = idx - 90112; int n = q >> 7, k = q & 127;
      p.d4[q] = f2bf(p.s4[k * 128 + n]);
    } else if (idx < 122880) {
      int q = idx - 106496; int n = q >> 7, k = q & 127;
      p.d5[q] = f2bf(p.s5[k * 128 + n]);
    } else if (idx < 139264) {
      int q = idx - 122880; int n = q >> 7, k = q & 127;
      p.dwe[q] = f2bf((n < 112) ? p.we[k * 112 + n] : 0.f);
    } else if (idx < 155648) {
      int q = idx - 139264; int o = q >> 7, h = q & 127;
      float v = 0.f;
      if (o < 64) v = p.t0[o * 128 + h];
      else if (o < 96) v = p.t1[(o - 64) * 128 + h];
      else if (o < 112) v = p.t2[(o - 96) * 128 + h];
      p.dtt[q] = f2bf(v);
    } else if (idx < 159744) {
      int q = idx - 155648; int n = q >> 6, k = q & 63;
      p.dp0[q] = f2bf(p.p0[k * 64 + n]);
    }
  }
}

// ---------------- prep: gather + Wigner rotate + softmax gates (wave-per-edge) ----------------
__global__ __launch_bounds__(256) void k_prep(
    const float* __restrict__ node_f, const float* __restrict__ edge_f,
    const float* __restrict__ D1g, const float* __restrict__ D2g,
    const float* __restrict__ mg_g, const float* __restrict__ Wg,
    const float* __restrict__ latg, const float* __restrict__ eohg,
    const int* __restrict__ eidx, const int* __restrict__ act,
    ushort* __restrict__ f_all, float* __restrict__ gf_out,
    ushort* __restrict__ lat_bf, ushort* __restrict__ mlp2_in) {
  __shared__ float sh[4][1244];
  const int w = threadIdx.x >> 6, lane = threadIdx.x & 63;
  const int e = blockIdx.x * 4 + w;
  float* s = sh[w];
  float* s_nc = s;
  float* s_ef = s + 240;
  float* s_nn = s + 480;
  float* s_d1 = s + 720;
  float* s_d2 = s + 729;
  float* s_mg = s + 754;
  float* s_lg = s + 818;
  ushort* row = (ushort*)(s + 828);
  const int ae = act[e];
  const int ec = eidx[ae], en = eidx[EDGES + ae];
  if (lane < 60) {
    ((float4v*)s_nc)[lane] = ((const float4v*)(node_f + (size_t)ec * 240))[lane];
    ((float4v*)s_ef)[lane] = ((const float4v*)(edge_f + (size_t)e * 240))[lane];
    ((float4v*)s_nn)[lane] = ((const float4v*)(node_f + (size_t)en * 240))[lane];
  }
  if (lane < 9)  s_d1[lane] = D1g[e * 9 + lane];
  if (lane < 25) s_d2[lane] = D2g[e * 25 + lane];
  s_mg[lane] = mg_g[e * 64 + lane];
  {
    const float* lp = latg + (size_t)ae * 128;
    float a0 = lp[2 * lane], a1 = lp[2 * lane + 1];
    ((uint*)lat_bf)[(size_t)e * 64 + lane] = (uint)f2bf(a0) | ((uint)f2bf(a1) << 16);
    const float* ep = eohg + (size_t)e * 128;
    a0 = ep[2 * lane]; a1 = ep[2 * lane + 1];
    ((uint*)mlp2_in)[(size_t)e * 128 + 64 + lane] = (uint)f2bf(a0) | ((uint)f2bf(a1) << 16);
  }
  {
    int k = lane & 7, hg = lane >> 3;
    float a = 0.f;
#pragma unroll
    for (int h = 0; h < 8; ++h) a += s_mg[hg * 8 + h] * Wg[(hg * 8 + h) * 8 + k];
    a += __shfl_xor(a, 8);
    a += __shfl_xor(a, 16);
    a += __shfl_xor(a, 32);
    if (lane < 8) s_lg[lane] = a;
  }
  if (lane < 12) {
    float m = s_lg[0];
    for (int j = 1; j < 8; ++j) m = fmaxf(m, s_lg[j]);
    float den = 0.f;
    for (int j = 0; j < 8; ++j) den += __expf(s_lg[j] - m);
    float v = 0.f;
    if (lane < 8) v = __expf(s_lg[lane] - m) / den;
    else if (lane == 8) v = 1.f;
    gf_out[e * 12 + lane] = v;
  }
  row[lane]       = f2bf(s_nc[lane]);
  row[64 + lane]  = f2bf(s_ef[lane]);
  row[128 + lane] = f2bf(s_nn[lane]);
  if (lane < 48) row[336 + lane] = 0;
  if (lane < 32) { row[672 + lane] = 0; row[800 + lane] = 0; }
#pragma unroll
  for (int it = 0; it < 5; ++it) {
    int q = lane + it * 64;
    if (q < 288) {
      int i = q / 96, c = q - i * 96;
      const float* src = (c < 32) ? s_nc : (c < 64) ? s_ef : s_nn;
      int base = 64 + (c & 31) * 3;
      float v = s_d1[i * 3] * src[base] + s_d1[i * 3 + 1] * src[base + 1] + s_d1[i * 3 + 2] * src[base + 2];
      int dst = (i == 0) ? 528 : (i == 1) ? 192 : 384;
      row[dst + c] = f2bf(v);
    }
  }
#pragma unroll
  for (int it = 0; it < 4; ++it) {
    int q = lane + it * 64;
    if (q < 240) {
      int i = q / 48, c = q - i * 48;
      const float* src = (c < 16) ? s_nc : (c < 32) ? s_ef : s_nn;
      int base = 160 + (c & 15) * 5;
      float v = s_d2[i * 5] * src[base] + s_d2[i * 5 + 1] * src[base + 1] +
                s_d2[i * 5 + 2] * src[base + 2] + s_d2[i * 5 + 3] * src[base + 3] +
                s_d2[i * 5 + 4] * src[base + 4];
      int dst = (i == 0) ? 752 : (i == 1) ? 624 : (i == 2) ? 288 : (i == 3) ? 480 : 704;
      row[dst + c] = f2bf(v);
    }
  }
  const uintx4* row4 = (const uintx4*)row;
  uintx4* dst4 = (uintx4*)(f_all + (size_t)e * 832);
#pragma unroll
  for (int it = 0; it < 2; ++it) {
    int q = lane + it * 64;
    if (q < 104) dst4[q] = row4[q];
  }
}

// ------- bf16 MFMA GEMM body (device) -------
// NGRP>1: A-fragments cached in registers; LDS holds B only (3-buf, counted vmcnt).
// NGRP==1: classic A+B double-buffered DMA staging.
template <int WAVES, int BM, int KZP, int SPG2, int NGRP, int NCOL, int FOFF, int ASTRIDE,
          bool HASBIAS, int EPI>
__device__ __forceinline__ void gemm_dev(
    int bid, char* sm,
    const ushort* __restrict__ A, const ushort* __restrict__ Bt,
    const float* __restrict__ gf, const float* __restrict__ bias,
    ushort* __restrict__ outb, int ob_stride, int ob_off,
    ushort* __restrict__ outb2) {
  constexpr int T = WAVES * 64;
  constexpr int WRS = WAVES / 2;
  constexpr int RPW = BM / WRS;
  constexpr int MI = RPW / 16;
  constexpr int NFW = NCOL / 32;
  constexpr int A_BYTES = BM * 128;
  constexpr int B_BYTES = NCOL * 128;
  constexpr int NT2 = KZP / 64;
  constexpr int AI = (BM * 8) / T;
  constexpr int NB = NCOL * 8;
  constexpr int BI = (NB + T - 1) / T;
  static_assert(NCOL % 32 == 0 && KZP % 64 == 0 && RPW % 16 == 0 && (BM * 8) % T == 0, "geom");
  const int tid = threadIdx.x;
  const int lane = tid & 63, wid = tid >> 6;
  const int wr = wid >> 1, wc = wid & 1;
  const int g16 = lane >> 4;
  const int lane15 = lane & 15;
  const int e0 = bid * BM;
  const f32x4 vzero = {0.f, 0.f, 0.f, 0.f};

  const char* bSrc[BI];
#pragma unroll
  for (int it = 0; it < BI; ++it) {
    int q = tid + it * T;
    if (q < NB) {
      int c = q >> 3, ch = (q & 7) ^ (c & 7);
      bSrc[it] = (const char*)(Bt + (size_t)c * KZP) + ch * 16;
    } else bSrc[it] = nullptr;
  }

  f32x4 accS[MI][NFW];
#pragma unroll
  for (int mi = 0; mi < MI; ++mi)
#pragma unroll
    for (int n = 0; n < NFW; ++n) accS[mi][n] = vzero;

  if constexpr (NGRP > 1) {
    char* b_lds = sm;
    f32x4 accC[MI][NFW];
#pragma unroll
    for (int mi = 0; mi < MI; ++mi)
#pragma unroll
      for (int n = 0; n < NFW; ++n) accC[mi][n] = vzero;

    float gfr[MI][4];
    auto gf_pref = [&](int gx) {
#pragma unroll
      for (int mi = 0; mi < MI; ++mi)
#pragma unroll
        for (int j = 0; j < 4; ++j)
          gfr[mi][j] = gf[(size_t)(e0 + wr * RPW + mi * 16 + g16 * 4 + j) * 12 + gx];
    };
    gf_pref(0);

    bf16x8 afr[SPG2][MI][2];
#pragma unroll
    for (int wi = 0; wi < SPG2; ++wi)
#pragma unroll
      for (int mi = 0; mi < MI; ++mi)
#pragma unroll
        for (int s = 0; s < 2; ++s)
          afr[wi][mi][s] = *(const bf16x8*)(
              A + (size_t)(e0 + wr * RPW + mi * 16 + lane15) * ASTRIDE + FOFF +
              wi * 64 + s * 32 + g16 * 8);

    auto stageB = [&](int t2, int buf) {
#pragma unroll
      for (int it = 0; it < BI; ++it) {
        int q = tid + it * T;
        if (q < NB)
          gload16(bSrc[it] + (size_t)t2 * 128, b_lds + buf * B_BYTES + (tid - lane + it * T) * 16);
      }
    };

    // per-wave load count per batch (wave-uniform): FULLI or FULLI+1
    constexpr int FULLI = NB / T;
    constexpr int PARTW = (NB % T) / 64;  // waves [0,PARTW) carry one extra load
    auto wait_tail = [&](bool issued) {
      if (!issued) { wait_vm<0>(); return; }
      if constexpr ((NB % T) == 0) {
        wait_vm<FULLI>();
      } else {
        if (wid < PARTW) wait_vm<FULLI + 1>(); else wait_vm<FULLI>();
      }
    };

    // prologue: 2-deep prefetch, then wait batch0 (allow batch1 in flight)
    stageB(0, 0);
    stageB(1, 1);
    wait_tail(true);
    __builtin_amdgcn_s_barrier();
    asm volatile("" ::: "memory");

    for (int g = 0; g < NGRP; ++g) {
#pragma unroll
      for (int wi = 0; wi < SPG2; ++wi) {
        int t2 = g * SPG2 + wi;
        bool issue = (t2 + 2) < NT2;
        if (issue) stageB(t2 + 2, (t2 + 2) % 3);
        const char* bL = b_lds + (t2 % 3) * B_BYTES;
#pragma unroll
        for (int s = 0; s < 2; ++s) {
#pragma unroll
          for (int n = 0; n < NFW; ++n) {
            int cB = (wc * NFW + n) * 16 + lane15;
            int slot = (s * 4 + g16) ^ (cB & 7);
            bf16x8 b = *(const bf16x8*)(bL + cB * 128 + slot * 16);
#pragma unroll
            for (int mi = 0; mi < MI; ++mi)
              accC[mi][n] = __builtin_amdgcn_mfma_f32_16x16x32_bf16(afr[wi][mi][s], b, accC[mi][n], 0, 0, 0);
          }
        }
        if (wi == SPG2 - 1) {
#pragma unroll
          for (int mi = 0; mi < MI; ++mi)
#pragma unroll
            for (int n = 0; n < NFW; ++n) {
#pragma unroll
              for (int j = 0; j < 4; ++j) accS[mi][n][j] += gfr[mi][j] * accC[mi][n][j];
              accC[mi][n] = vzero;
            }
          if (g + 1 < NGRP) gf_pref(g + 1);
        }
        // counted wait: batches <= t2+1 complete; batch t2+2 stays in flight
        wait_tail(issue);
        __builtin_amdgcn_s_barrier();
        asm volatile("" ::: "memory");
      }
    }
  } else {
    char* a_lds = sm;
    char* b_lds = sm + 2 * A_BYTES;
    const char* aSrc[AI];
#pragma unroll
    for (int it = 0; it < AI; ++it) {
      int q = tid + it * T;
      int r = q >> 3, ch = (q & 7) ^ (r & 7);
      aSrc[it] = (const char*)(A + (size_t)(e0 + r) * ASTRIDE + FOFF) + ch * 16;
    }
    auto stage = [&](int t2, int buf) {
#pragma unroll
      for (int it = 0; it < AI; ++it)
        gload16(aSrc[it] + t2 * 128, a_lds + buf * A_BYTES + (tid - lane + it * T) * 16);
#pragma unroll
      for (int it = 0; it < BI; ++it) {
        int q = tid + it * T;
        if (q < NB)
          gload16(bSrc[it] + t2 * 128, b_lds + buf * B_BYTES + (tid - lane + it * T) * 16);
      }
    };
    stage(0, 0);
    __syncthreads();
    int cur = 0;
    for (int t2 = 0; t2 < NT2; ++t2) {
      if (t2 + 1 < NT2) stage(t2 + 1, cur ^ 1);
      const char* aL = a_lds + cur * A_BYTES;
      const char* bL = b_lds + cur * B_BYTES;
#pragma unroll
      for (int s = 0; s < 2; ++s) {
        bf16x8 a[MI];
#pragma unroll
        for (int mi = 0; mi < MI; ++mi) {
          int rA = wr * RPW + mi * 16 + lane15;
          int slot = (s * 4 + g16) ^ (rA & 7);
          a[mi] = *(const bf16x8*)(aL + rA * 128 + slot * 16);
        }
#pragma unroll
        for (int n = 0; n < NFW; ++n) {
          int cB = (wc * NFW + n) * 16 + lane15;
          int slot = (s * 4 + g16) ^ (cB & 7);
          bf16x8 b = *(const bf16x8*)(bL + cB * 128 + slot * 16);
#pragma unroll
          for (int mi = 0; mi < MI; ++mi)
            accS[mi][n] = __builtin_amdgcn_mfma_f32_16x16x32_bf16(a[mi], b, accS[mi][n], 0, 0, 0);
        }
      }
      __syncthreads();
      cur ^= 1;
    }
  }

#pragma unroll
  for (int mi = 0; mi < MI; ++mi) {
    const int row0 = wr * RPW + mi * 16 + g16 * 4;
#pragma unroll
    for (int n = 0; n < NFW; ++n) {
      const int c = (wc * NFW + n) * 16 + lane15;
      float bv = 0.f;
      if constexpr (HASBIAS) bv = bias[c];
#pragma unroll
      for (int j = 0; j < 4; ++j) {
        float v = accS[mi][n][j] + bv;
        const int er = e0 + row0 + j;
        if constexpr (EPI == 1) v = v / (1.f + __expf(-v));
        outb[(size_t)er * ob_stride + ob_off + c] = f2bf(v);
        if constexpr (EPI == 2) {
          if ((wc * NFW + n) * 16 < 64)
            outb2[(size_t)er * 256 + c] = f2bf(v / (1.f + __expf(-v)));
        }
      }
    }
  }
}

// ---- merged MoE GEMMs: one launch, 512-thread blocks (R17 geometry + 3-buf counted vmcnt) ----
struct MoeArgs {
  const ushort *f_all, *B0t, *B1t, *B2t;
  const float* gfb;
  ushort *moeout, *m2in;
};
__global__ __launch_bounds__(512) void k_moe(MoeArgs a) {
  __shared__ char sm[3 * 160 * 128 + 16];  // max B triple-buffer (moe0)
  int bid = blockIdx.x;
  if (bid < 512) {
    gemm_dev<8, 128, 3456, 6, 9, 160, 0, 832, false, 2>(
        bid, sm, a.f_all, a.B0t, a.gfb, nullptr, a.moeout, 288, 0, a.m2in);
  } else if (bid < 1024) {
    gemm_dev<8, 128, 2880, 5, 9, 96, 384, 832, false, 0>(
        bid - 512, sm, a.f_all, a.B1t, a.gfb, nullptr, a.moeout, 288, 160, nullptr);
  } else {
    gemm_dev<8, 128, 1152, 2, 9, 32, 704, 832, false, 0>(
        bid - 1024, sm, a.f_all, a.B2t, a.gfb, nullptr, a.moeout, 288, 256, nullptr);
  }
}

// ---- merged small GEMMs ----
struct Small3Args {
  const ushort *latbf, *Wet, *m2in, *Ttb, *P0t;
  const float* b0;
  ushort *wbuf, *tbuf, *m1in;
};
__global__ __launch_bounds__(256) void k_small3(Small3Args a) {
  __shared__ char sm[49168];
  int bid = blockIdx.x;
  if (bid < 1024) {
    gemm_dev<4, 64, 128, 1, 1, 128, 0, 128, false, 0>(
        bid, sm, a.latbf, a.Wet, nullptr, nullptr, a.wbuf, 128, 0, nullptr);
  } else if (bid < 2048) {
    gemm_dev<4, 64, 128, 1, 1, 128, 128, 256, false, 0>(
        bid - 1024, sm, a.m2in, a.Ttb, nullptr, nullptr, a.tbuf, 128, 0, nullptr);
  } else {
    gemm_dev<4, 64, 64, 1, 1, 64, 0, 256, true, 0>(
        bid - 2048, sm, a.m2in, a.P0t, nullptr, a.b0, a.m1in, 192, 128, nullptr);
  }
}

// ---------------- fused 6-layer MLP: 32 edges/block, X in LDS, W double-buffered ----------
struct MlpArgs {
  const ushort *m1in, *m2in, *Wt1, *Wt2, *Wt3, *Wt4, *Wt5, *Wt6;
  const float *b1, *b2, *b3, *b4, *b5, *b6;
  const int* act;
  const float *cutg, *latg;
  float* out_lat;
};
__global__ __launch_bounds__(256) void k_mlp(MlpArgs A) {
  __shared__ char sm[61440];
  char* Xa = sm;
  char* Xb = sm + 12288;
  char* Xe = sm + 20480;
  char* W0 = sm + 28672;
  char* W1 = sm + 45056;
  const int tid = threadIdx.x;
  const int lane = tid & 63, w = tid >> 6;
  const int wr = w >> 1, wc = w & 1;
  const int lane15 = lane & 15, g16 = lane >> 4;
  const int e32 = blockIdx.x * 32;
  const f32x4 vzero = {0.f, 0.f, 0.f, 0.f};

  auto stage_w = [&](const ushort* Wt, int K2, int t2, char* dst) {
#pragma unroll
    for (int it = 0; it < 4; ++it) {
      int q = tid + it * 256;
      int c = q >> 3, ch = (q & 7) ^ (c & 7);
      gload16((const char*)Wt + (size_t)c * K2 + t2 * 128 + ch * 16,
              dst + (w + it * 4) * 1024);
    }
  };
  {
#pragma unroll
    for (int it = 0; it < 3; ++it) {
      int q = tid + it * 256;
      int r = q / 24, c24 = q - r * 24;
      int t2 = c24 >> 3, ch = (c24 & 7) ^ (r & 7);
      gload16((const char*)A.m1in + (size_t)(e32 + r) * 384 + t2 * 128 + ch * 16,
              Xa + (w + it * 4) * 1024);
    }
#pragma unroll
    for (int it = 0; it < 2; ++it) {
      int q = tid + it * 256;
      int r = q >> 4, c16 = q & 15;
      int t2 = c16 >> 3, ch = (c16 & 7) ^ (r & 7);
      gload16((const char*)A.m2in + (size_t)(e32 + r) * 512 + 256 + t2 * 128 + ch * 16,
              Xe + (w + it * 4) * 1024);
    }
  }
  stage_w(A.Wt1, 384, 0, W0);
  __syncthreads();

  f32x4 acc[4];
#pragma unroll
  for (int n = 0; n < 4; ++n) acc[n] = vzero;

  auto compute = [&](const char* xin, int xstride, int t2loc, const char* wl) {
#pragma unroll
    for (int s = 0; s < 2; ++s) {
      int row = wr * 16 + lane15;
      bf16x8 a = *(const bf16x8*)(xin + row * xstride + t2loc * 128 + (((s * 4 + g16) ^ (row & 7)) << 4));
#pragma unroll
      for (int n = 0; n < 4; ++n) {
        int cB = wc * 64 + n * 16 + lane15;
        bf16x8 b = *(const bf16x8*)(wl + cB * 128 + (((s * 4 + g16) ^ (cB & 7)) << 4));
        acc[n] = __builtin_amdgcn_mfma_f32_16x16x32_bf16(a, b, acc[n], 0, 0, 0);
      }
    }
  };
  auto epi_x = [&](const float* bias, char* xout, int xstride, bool dosilu) {
#pragma unroll
    for (int n = 0; n < 4; ++n) {
      int c = wc * 64 + n * 16 + lane15;
      float bv = bias[c];
      int ch = (n * 16 + lane15) >> 3;
#pragma unroll
      for (int j = 0; j < 4; ++j) {
        int row = wr * 16 + g16 * 4 + j;
        float v = acc[n][j] + bv;
        if (dosilu) v = v / (1.f + __expf(-v));
        *(ushort*)(xout + row * xstride + wc * 128 + ((ch ^ (row & 7)) << 4) + ((lane15 & 7) << 1)) = f2bf(v);
      }
      acc[n] = vzero;
    }
  };

  stage_w(A.Wt1, 384, 1, W1); compute(Xa, 384, 0, W0); __syncthreads();
  stage_w(A.Wt1, 384, 2, W0); compute(Xa, 384, 1, W1); __syncthreads();
  stage_w(A.Wt2, 256, 0, W1); compute(Xa, 384, 2, W0); epi_x(A.b1, Xb, 256, true); __syncthreads();
  stage_w(A.Wt2, 256, 1, W0); compute(Xb, 256, 0, W1); __syncthreads();
  stage_w(A.Wt3, 256, 0, W1); compute(Xb, 256, 1, W0); epi_x(A.b2, Xa, 384, true); __syncthreads();
  stage_w(A.Wt3, 256, 1, W0); compute(Xa, 384, 0, W1); __syncthreads();
  stage_w(A.Wt4, 512, 0, W1); compute(Xa, 384, 1, W0); epi_x(A.b3, Xb, 256, false); __syncthreads();
  stage_w(A.Wt4, 512, 1, W0); compute(Xb, 256, 0, W1); __syncthreads();
  stage_w(A.Wt4, 512, 2, W1); compute(Xb, 256, 1, W0); __syncthreads();
  stage_w(A.Wt4, 512, 3, W0); compute(Xe, 256, 0, W1); __syncthreads();
  stage_w(A.Wt5, 256, 0, W1); compute(Xe, 256, 1, W0); epi_x(A.b4, Xa, 384, true); __syncthreads();
  stage_w(A.Wt5, 256, 1, W0); compute(Xa, 384, 0, W1); __syncthreads();
  stage_w(A.Wt6, 256, 0, W1); compute(Xa, 384, 1, W0); epi_x(A.b5, Xb, 256, true); __syncthreads();
  stage_w(A.Wt6, 256, 1, W0); compute(Xb, 256, 0, W1); __syncthreads();
  compute(Xb, 256, 1, W0);
#pragma unroll
  for (int n = 0; n < 4; ++n) {
    int c = wc * 64 + n * 16 + lane15;
    float bv = A.b6[c];
#pragma unroll
    for (int j = 0; j < 4; ++j) {
      int row = wr * 16 + g16 * 4 + j;
      int er = e32 + row;
      int ae = A.act[er];
      float v = acc[n][j] + bv;
      A.out_lat[(size_t)ae * 128 + c] = C_NEW * A.cutg[ae] * v + C_OLD * A.latg[(size_t)ae * 128 + c];
    }
  }
}

// ------ post-MoE + final combine: wave-per-edge, 8 edges/block; P-mixes via 3 MFMAs ------
__global__ __launch_bounds__(512) void k_postf(
    const ushort* __restrict__ moeout,
    const float* __restrict__ D1g, const float* __restrict__ D2g,
    const float* __restrict__ latg, const int* __restrict__ act,
    const float* __restrict__ P1, const float* __restrict__ P2,
    const ushort* __restrict__ wbuf, const float* __restrict__ beg,
    const float* __restrict__ lng, const float* __restrict__ lnb,
    const ushort* __restrict__ tbufp, const float* __restrict__ efg,
    ushort* __restrict__ m1in, float* __restrict__ out_edge) {
  __shared__ float SM[1136 + 8 * 920];
  ushort* Btab = (ushort*)SM;
  float* be_s = SM + 768;
  float* lng_s = SM + 880;
  float* lnb_s = SM + 1008;
  const int t = threadIdx.x;
  const int w = t >> 6, lane = t & 63;
  float* Wp = SM + 1136 + w * 920;
  float* o   = Wp;
  float* row = Wp + 224;
  float* sg  = Wp + 464;
  float* d1  = Wp + 512;
  float* d2  = Wp + 524;
  ushort* wvh = (ushort*)(Wp + 552);
  ushort* tvh = (ushort*)(Wp + 608);
  ushort* tile = (ushort*)(Wp + 664);
  const int e = blockIdx.x * 8 + w;
  const int ae = act[e];
  const f32x4 vzero = {0.f, 0.f, 0.f, 0.f};

  float ef[4];
  ef[0] = efg[(size_t)e * 240 + lane];
  ef[1] = efg[(size_t)e * 240 + 64 + lane];
  ef[2] = efg[(size_t)e * 240 + 128 + lane];
  ef[3] = (lane < 48) ? efg[(size_t)e * 240 + 192 + lane] : 0.f;
  float2v ll = ((const float2v*)(latg + (size_t)ae * 128))[lane];

  if (lane < 28) {
    uintx4 raw = *(const uintx4*)(moeout + (size_t)e * 288 + 64 + lane * 8);
    float* dst = o + lane * 8;
#pragma unroll
    for (int j = 0; j < 4; ++j) {
      uint u = raw[j];
      dst[2 * j] = bf2f((ushort)(u & 0xFFFF));
      dst[2 * j + 1] = bf2f((ushort)(u >> 16));
    }
  }
  if (lane < 14) {
    *(uintx4*)((char*)wvh + lane * 16) = *(const uintx4*)(wbuf + (size_t)e * 128 + lane * 8);
    *(uintx4*)((char*)tvh + lane * 16) = *(const uintx4*)(tbufp + (size_t)e * 128 + lane * 8);
  }
  if (lane < 8) {
    uintx4 raw = *(const uintx4*)(m1in + (size_t)e * 192 + 128 + lane * 8);
    float* dst = row + lane * 8;
#pragma unroll
    for (int j = 0; j < 4; ++j) {
      uint u = raw[j];
      dst[2 * j] = bf2f((ushort)(u & 0xFFFF));
      dst[2 * j + 1] = bf2f((ushort)(u >> 16));
    }
  }
  if (lane < 9)  d1[lane] = D1g[(size_t)e * 9 + lane];
  if (lane < 25) d2[lane] = D2g[(size_t)e * 25 + lane];
  if (lane < 48) sg[lane] = 1.f / (1.f + __expf(-o[lane]));

#pragma unroll
  for (int i = 0; i < 3; ++i) {
    int q = t + i * 512;
    int tbl = q >> 9, idx = q & 511;
    int d = idx >> 5, c = idx & 31;
    float v;
    if (tbl == 0) v = P1[c * 32 + d];
    else if (tbl == 1) v = P1[c * 32 + 16 + d];
    else v = (c < 16) ? P2[c * 16 + d] : 0.f;
    Btab[tbl * 512 + d * 32 + (((c >> 3) ^ (d & 3)) << 3) + (c & 7)] = f2bf(v);
  }
  if (t < 368) {
    if (t < 112) be_s[t] = beg[t];
    else if (t < 240) lng_s[t - 112] = lng[t - 112];
    else lnb_s[t - 240] = lnb[t - 240];
  }

  float sum = ll[0] + ll[1];
  float sq = ll[0] * ll[0] + ll[1] * ll[1];
#pragma unroll
  for (int m = 32; m > 0; m >>= 1) {
    sum += __shfl_xor(sum, m);
    sq += __shfl_xor(sq, m);
  }
  const float mu = sum * (1.f / 128.f);
  const float rs = rsqrtf(sq * (1.f / 128.f) - mu * mu + 1e-5f);

  __syncthreads();

  {
    int i = 2 * lane;
    float l0 = (ll[0] - mu) * rs * lng_s[i] + lnb_s[i];
    float l1 = (ll[1] - mu) * rs * lng_s[i + 1] + lnb_s[i + 1];
    ((uint*)m1in)[(size_t)e * 96 + lane] = (uint)f2bf(l0) | ((uint)f2bf(l1) << 16);
  }
#pragma unroll
  for (int rr = 0; rr < 2; ++rr) {
    int r = lane + rr * 64;
    if (r < 96) {
      int m = r >> 5, c = r & 31;
      float v = d1[m] * o[144 + c] + d1[3 + m] * o[48 + c] + d1[6 + m] * o[96 + c];
      tile[m * 32 + (((c >> 3) ^ (m & 3)) << 3) + (c & 7)] = f2bf(v * sg[c]);
    }
  }
#pragma unroll
  for (int rr = 0; rr < 3; ++rr) {
    int r = lane + rr * 64;
    if (r < 160) {
      int rw = 3 + (r >> 5), c = r & 31;
      ushort hv = 0;
      if (c < 16) {
        int m = rw - 3;
        float v = d2[m] * o[208 + c] + d2[5 + m] * o[176 + c] + d2[10 + m] * o[80 + c] +
                  d2[15 + m] * o[128 + c] + d2[20 + m] * o[192 + c];
        hv = f2bf(v * sg[32 + c]);
      }
      tile[rw * 32 + (((c >> 3) ^ (rw & 3)) << 3) + (c & 7)] = hv;
    }
  }
  {
    const int r15 = lane & 15, g = lane >> 4;
    const int fslot = (g ^ (r15 & 3)) << 3;
    bf16x8 afr = *(const bf16x8*)(tile + r15 * 32 + fslot);
    bf16x8 b1a = *(const bf16x8*)(Btab + r15 * 32 + fslot);
    bf16x8 b1b = *(const bf16x8*)(Btab + 512 + r15 * 32 + fslot);
    bf16x8 b2p = *(const bf16x8*)(Btab + 1024 + r15 * 32 + fslot);
    f32x4 v1a = __builtin_amdgcn_mfma_f32_16x16x32_bf16(afr, b1a, vzero, 0, 0, 0);
    f32x4 v1b = __builtin_amdgcn_mfma_f32_16x16x32_bf16(afr, b1b, vzero, 0, 0, 0);
    f32x4 v2r = __builtin_amdgcn_mfma_f32_16x16x32_bf16(afr, b2p, vzero, 0, 0, 0);
    if (g == 0) {
      float s1 = bf2f(wvh[64 + r15]) + be_s[64 + r15];
      row[64 + r15 * 3 + 0] = v1a[0] * s1;
      row[64 + r15 * 3 + 1] = v1a[1] * s1;
      row[64 + r15 * 3 + 2] = v1a[2] * s1;
      float s2 = bf2f(wvh[80 + r15]) + be_s[80 + r15];
      row[64 + (16 + r15) * 3 + 0] = v1b[0] * s2;
      row[64 + (16 + r15) * 3 + 1] = v1b[1] * s2;
      row[64 + (16 + r15) * 3 + 2] = v1b[2] * s2;
      float s3 = bf2f(wvh[96 + r15]) + be_s[96 + r15];
      row[160 + r15 * 5 + 0] = v2r[3] * s3;
    } else if (g == 1) {
      float s3 = bf2f(wvh[96 + r15]) + be_s[96 + r15];
      row[160 + r15 * 5 + 1] = v2r[0] * s3;
      row[160 + r15 * 5 + 2] = v2r[1] * s3;
      row[160 + r15 * 5 + 3] = v2r[2] * s3;
      row[160 + r15 * 5 + 4] = v2r[3] * s3;
    }
  }
  row[lane] = row[lane] * (bf2f(wvh[lane]) + be_s[lane]);
#pragma unroll
  for (int r = 0; r < 4; ++r) {
    int d = lane + r * 64;
    if (r < 3 || lane < 48) {
      float v = C_OLD * ef[r] + C_NEW * row[d];
      int ti = (d < 64) ? d : (d < 160) ? 64 + (d - 64) / 3 : 96 + (d - 160) / 5;
      float f = bf2f(tvh[ti]) * T_SCALE;
      out_edge[(size_t)e * 240 + d] = v * (1.f + f);
    }
  }
}

extern "C" void kernel_launch(void* const* d_in, const int* in_sizes, int n_in,
                              void* d_out, int out_size, void* d_ws, size_t ws_size,
                              hipStream_t stream) {
  const float* latents = (const float*)d_in[0];
  const float* node_f  = (const float*)d_in[1];
  const float* edge_f  = (const float*)d_in[3];
  const float* cutoff  = (const float*)d_in[5];
  const float* eoh     = (const float*)d_in[6];
  const float* D1      = (const float*)d_in[7];
  const float* D2      = (const float*)d_in[8];
  const float* mg      = (const float*)d_in[9];
  const int*   eidx    = (const int*)d_in[10];
  const int*   act     = (const int*)d_in[11];
  const float* Wg      = (const float*)d_in[12];
  const float* W0      = (const float*)d_in[13];
  const float* W1r     = (const float*)d_in[14];
  const float* W1i     = (const float*)d_in[15];
  const float* W2r     = (const float*)d_in[16];
  const float* W2i     = (const float*)d_in[17];
  const float* P0      = (const float*)d_in[18];
  const float* b0      = (const float*)d_in[19];
  const float* P1      = (const float*)d_in[20];
  const float* P2      = (const float*)d_in[21];
  const float* We      = (const float*)d_in[22];
  const float* be      = (const float*)d_in[23];
  const float* lng     = (const float*)d_in[24];
  const float* lnb     = (const float*)d_in[25];
  const float* M1W0_   = (const float*)d_in[26];
  const float* M1b0_   = (const float*)d_in[27];
  const float* M1W1_   = (const float*)d_in[28];
  const float* M1b1_   = (const float*)d_in[29];
  const float* M1W2_   = (const float*)d_in[30];
  const float* M1b2_   = (const float*)d_in[31];
  const float* M2W0_   = (const float*)d_in[32];
  const float* M2b0_   = (const float*)d_in[33];
  const float* M2W1_   = (const float*)d_in[34];
  const float* M2b1_   = (const float*)d_in[35];
  const float* M2W2_   = (const float*)d_in[36];
  const float* M2b2_   = (const float*)d_in[37];
  const float* T0      = (const float*)d_in[38];
  const float* T1      = (const float*)d_in[39];
  const float* T2      = (const float*)d_in[40];

  float* out_edge = (float*)d_out;
  float* out_lat  = out_edge + (size_t)EDGES * 240;
  float* out_d1   = out_lat + (size_t)EDGES * 128;
  float* out_d2   = out_d1 + (size_t)EDGES * 9;

  char* ws = (char*)d_ws;
  size_t off = 0;
  auto alloc = [&](size_t bytes) -> char* {
    char* p = ws + off;
    off += (bytes + 255) & ~size_t(255);
    return p;
  };
  ushort* f_all  = (ushort*)alloc((size_t)EDGES * 832 * 2);
  float*  gfb    = (float*) alloc((size_t)EDGES * 12 * 4);
  ushort* moeout = (ushort*)alloc((size_t)EDGES * 288 * 2);
  ushort* m2in   = (ushort*)alloc((size_t)EDGES * 256 * 2);
  ushort* latbf  = (ushort*)alloc((size_t)EDGES * 128 * 2);
  ushort* wbuf   = (ushort*)alloc((size_t)EDGES * 128 * 2);
  ushort* B0t    = (ushort*)alloc(160 * 3456 * 2);
  ushort* B1t    = (ushort*)alloc(96 * 2880 * 2);
  ushort* B2t    = (ushort*)alloc(32 * 1152 * 2);
  ushort* Wt1    = (ushort*)alloc(128 * 192 * 2);
  ushort* Wt2    = (ushort*)alloc(128 * 128 * 2);
  ushort* Wt3    = (ushort*)alloc(128 * 128 * 2);
  ushort* Wt4    = (ushort*)alloc(128 * 256 * 2);
  ushort* Wt5    = (ushort*)alloc(128 * 128 * 2);
  ushort* Wt6    = (ushort*)alloc(128 * 128 * 2);
  ushort* Wet    = (ushort*)alloc(128 * 128 * 2);
  ushort* Ttb    = (ushort*)alloc(128 * 128 * 2);
  ushort* P0t    = (ushort*)alloc(64 * 64 * 2);

  ushort* m1in = f_all;   // E*192 overlay (dead after MoE GEMMs)
  ushort* tbuf = latbf;   // reused after We-GEMM

  hipMemcpyAsync(out_d1, (const void*)D1, (size_t)EDGES * 9 * 4, hipMemcpyDeviceToDevice, stream);
  hipMemcpyAsync(out_d2, (const void*)D2, (size_t)EDGES * 25 * 4, hipMemcpyDeviceToDevice, stream);

  if (ws_size < off) return;

  PackArgs pk = {W0, W1r, W1i, W2r, W2i,
                 M1W0_, M1W1_, M1W2_, M2W0_, M2W1_, M2W2_, We, T0, T1, T2, P0,
                 B0t, B1t, B2t,
                 Wt1, Wt2, Wt3, Wt4, Wt5, Wt6, Wet, Ttb, P0t};
  k_pack<<<4008, 256, 0, stream>>>(pk);

  k_prep<<<EDGES / 4, 256, 0, stream>>>(node_f, edge_f, D1, D2, mg, Wg, latents, eoh,
                                        eidx, act, f_all, gfb, latbf, m2in);

  // merged MoE GEMMs: BM=128, 8 waves/block, 3-buf counted-vmcnt pipeline
  MoeArgs mo = {f_all, B0t, B1t, B2t, gfb, moeout, m2in};
  k_moe<<<1536, 512, 0, stream>>>(mo);

  // merged small GEMMs: lat@We | eoh@T^T | scs@P0+b0 in one launch
  Small3Args s3 = {latbf, Wet, m2in, Ttb, P0t, b0, wbuf, tbuf, m1in};
  k_small3<<<3072, 256, 0, stream>>>(s3);

  // fused post + final combine (wave-per-edge, 8 edges/block, MFMA P-mixes)
  k_postf<<<EDGES / 8, 512, 0, stream>>>(moeout, D1, D2, latents, act, P1, P2,
                                         wbuf, be, lng, lnb, tbuf, edge_f, m1in, out_edge);

  // fused 6-layer MLP chain (final layer fuses latent update into out_lat)
  MlpArgs ma = {m1in, m2in, Wt1, Wt2, Wt3, Wt4, Wt5, Wt6,
                M1b0_, M1b1_, M1b2_, M2b0_, M2b1_, M2b2_,
                act, cutoff, latents, out_lat};
  k_mlp<<<EDGES / 32, 256, 0, stream>>>(ma);
}

// Round 24
// 409.232 us; speedup vs baseline: 1.0693x; 1.0277x over previous
//
#include <hip/hip_runtime.h>
#include <hip/hip_bf16.h>
#include <stdint.h>

#define EDGES 65536

typedef unsigned int uint;
typedef unsigned short ushort;
using bf16x8 = __attribute__((ext_vector_type(8))) __bf16;
using f32x4  = __attribute__((ext_vector_type(4))) float;
using uintx4 = __attribute__((ext_vector_type(4))) uint;
using float4v = __attribute__((ext_vector_type(4))) float;
using float2v = __attribute__((ext_vector_type(2))) float;

#define C_OLD 0.8944271909999159f
#define C_NEW 0.4472135954999579f
#define T_SCALE 0.08838834764831845f

__device__ __forceinline__ ushort f2bf(float f) {
  uint x = __builtin_bit_cast(uint, f);
  uint r = x + 0x7FFFu + ((x >> 16) & 1u);
  return (ushort)(r >> 16);
}
__device__ __forceinline__ float bf2f(ushort u) {
  uint x = (uint)u << 16;
  return __builtin_bit_cast(float, x);
}
__device__ __forceinline__ void gload16(const void* g, void* l) {
  __builtin_amdgcn_global_load_lds(
      (const __attribute__((address_space(1))) void*)g,
      (__attribute__((address_space(3))) void*)l, 16, 0, 0);
}
// counted-vmcnt wait (immediate must be a literal per variant)
template <int N> __device__ __forceinline__ void wait_vm() {
  if constexpr (N <= 0) asm volatile("s_waitcnt vmcnt(0)" ::: "memory");
  else if constexpr (N == 1) asm volatile("s_waitcnt vmcnt(1)" ::: "memory");
  else if constexpr (N == 2) asm volatile("s_waitcnt vmcnt(2)" ::: "memory");
  else if constexpr (N == 3) asm volatile("s_waitcnt vmcnt(3)" ::: "memory");
  else asm volatile("s_waitcnt vmcnt(4)" ::: "memory");
}

// ---------------- merged front kernel: weight pack + prep (+ D1/D2 passthrough) ----------------
struct PackArgs {
  const float *W0, *W1r, *W1i, *W2r, *W2i;
  const float *s0, *s1, *s2, *s3, *s4, *s5, *we, *t0, *t1, *t2, *p0;
  ushort *B0, *B1, *B2;
  ushort *d0, *d1, *d2, *d3, *d4, *d5, *dwe, *dtt, *dp0;
};
#define PACK_BLOCKS 4008
__global__ __launch_bounds__(256) void k_front(
    PackArgs p,
    const float* __restrict__ node_f, const float* __restrict__ edge_f,
    const float* __restrict__ D1g, const float* __restrict__ D2g,
    const float* __restrict__ mg_g, const float* __restrict__ Wg,
    const float* __restrict__ latg, const float* __restrict__ eohg,
    const int* __restrict__ eidx, const int* __restrict__ act,
    ushort* __restrict__ f_all, float* __restrict__ gf_out,
    ushort* __restrict__ lat_bf, ushort* __restrict__ mlp2_in,
    float* __restrict__ out_d1, float* __restrict__ out_d2) {
  __shared__ float sh[4][1244];
  int bid = blockIdx.x;
  if (bid < PACK_BLOCKS) {
    // ---------- pack branch ----------
    if (bid < 2160) {
      int idx = bid * 256 + threadIdx.x;
      if (idx >= 160 * 3456) return;
      int o = idx / 3456, kf = idx - o * 3456;
      int k = kf / 384, f = kf - k * 384;
      float v = (f < 336) ? p.W0[k * 53760 + f * 160 + o] : 0.f;
      p.B0[idx] = f2bf(v);
    } else if (bid < 3240) {
      int idx = (bid - 2160) * 256 + threadIdx.x;
      if (idx >= 96 * 2880) return;
      int c = idx / 2880, kf = idx - c * 2880;
      int k = kf / 320, f = kf - k * 320;
      float v = 0.f;
      if (f < 288) {
        if (c < 48) v = (f < 144) ? p.W1r[k * 6912 + f * 48 + c] : -p.W1i[k * 6912 + (f - 144) * 48 + c];
        else        v = (f < 144) ? p.W1i[k * 6912 + f * 48 + (c - 48)] : p.W1r[k * 6912 + (f - 144) * 48 + (c - 48)];
      }
      p.B1[idx] = f2bf(v);
    } else if (bid < 3384) {
      int idx = (bid - 3240) * 256 + threadIdx.x;
      if (idx >= 32 * 1152) return;
      int c = idx / 1152, kf = idx - c * 1152;
      int k = kf / 128, f = kf - k * 128;
      float v = 0.f;
      if (f < 96) {
        if (c < 16) v = (f < 48) ? p.W2r[k * 768 + f * 16 + c] : -p.W2i[k * 768 + (f - 48) * 16 + c];
        else        v = (f < 48) ? p.W2i[k * 768 + f * 16 + (c - 16)] : p.W2r[k * 768 + (f - 48) * 16 + (c - 16)];
      }
      p.B2[idx] = f2bf(v);
    } else {
      int idx = (bid - 3384) * 256 + threadIdx.x;
      if (idx < 24576) {
        int n = idx / 192, k = idx - n * 192;
        p.d0[idx] = f2bf(p.s0[k * 128 + n]);
      } else if (idx < 40960) {
        int q = idx - 24576; int n = q >> 7, k = q & 127;
        p.d1[q] = f2bf(p.s1[k * 128 + n]);
      } else if (idx < 57344) {
        int q = idx - 40960; int n = q >> 7, k = q & 127;
        p.d2[q] = f2bf(p.s2[k * 128 + n]);
      } else if (idx < 90112) {
        int q = idx - 57344; int n = q / 256, k = q - n * 256;
        p.d3[q] = f2bf(p.s3[k * 128 + n]);
      } else if (idx < 106496) {
        int q = idx - 90112; int n = q >> 7, k = q & 127;
        p.d4[q] = f2bf(p.s4[k * 128 + n]);
      } else if (idx < 122880) {
        int q = idx - 106496; int n = q >> 7, k = q & 127;
        p.d5[q] = f2bf(p.s5[k * 128 + n]);
      } else if (idx < 139264) {
        int q = idx - 122880; int n = q >> 7, k = q & 127;
        p.dwe[q] = f2bf((n < 112) ? p.we[k * 112 + n] : 0.f);
      } else if (idx < 155648) {
        int q = idx - 139264; int o = q >> 7, h = q & 127;
        float v = 0.f;
        if (o < 64) v = p.t0[o * 128 + h];
        else if (o < 96) v = p.t1[(o - 64) * 128 + h];
        else if (o < 112) v = p.t2[(o - 96) * 128 + h];
        p.dtt[q] = f2bf(v);
      } else if (idx < 159744) {
        int q = idx - 155648; int n = q >> 6, k = q & 63;
        p.dp0[q] = f2bf(p.p0[k * 64 + n]);
      }
    }
    return;
  }
  // ---------- prep branch (wave-per-edge) ----------
  const int w = threadIdx.x >> 6, lane = threadIdx.x & 63;
  const int e = (bid - PACK_BLOCKS) * 4 + w;
  float* s = sh[w];
  float* s_nc = s;
  float* s_ef = s + 240;
  float* s_nn = s + 480;
  float* s_d1 = s + 720;
  float* s_d2 = s + 729;
  float* s_mg = s + 754;
  float* s_lg = s + 818;
  ushort* row = (ushort*)(s + 828);
  const int ae = act[e];
  const int ec = eidx[ae], en = eidx[EDGES + ae];
  if (lane < 60) {
    ((float4v*)s_nc)[lane] = ((const float4v*)(node_f + (size_t)ec * 240))[lane];
    ((float4v*)s_ef)[lane] = ((const float4v*)(edge_f + (size_t)e * 240))[lane];
    ((float4v*)s_nn)[lane] = ((const float4v*)(node_f + (size_t)en * 240))[lane];
  }
  if (lane < 9)  { float v = D1g[e * 9 + lane];  s_d1[lane] = v; out_d1[(size_t)e * 9 + lane] = v; }
  if (lane < 25) { float v = D2g[e * 25 + lane]; s_d2[lane] = v; out_d2[(size_t)e * 25 + lane] = v; }
  s_mg[lane] = mg_g[e * 64 + lane];
  {
    const float* lp = latg + (size_t)ae * 128;
    float a0 = lp[2 * lane], a1 = lp[2 * lane + 1];
    ((uint*)lat_bf)[(size_t)e * 64 + lane] = (uint)f2bf(a0) | ((uint)f2bf(a1) << 16);
    const float* ep = eohg + (size_t)e * 128;
    a0 = ep[2 * lane]; a1 = ep[2 * lane + 1];
    ((uint*)mlp2_in)[(size_t)e * 128 + 64 + lane] = (uint)f2bf(a0) | ((uint)f2bf(a1) << 16);
  }
  {
    int k = lane & 7, hg = lane >> 3;
    float a = 0.f;
#pragma unroll
    for (int h = 0; h < 8; ++h) a += s_mg[hg * 8 + h] * Wg[(hg * 8 + h) * 8 + k];
    a += __shfl_xor(a, 8);
    a += __shfl_xor(a, 16);
    a += __shfl_xor(a, 32);
    if (lane < 8) s_lg[lane] = a;
  }
  if (lane < 12) {
    float m = s_lg[0];
    for (int j = 1; j < 8; ++j) m = fmaxf(m, s_lg[j]);
    float den = 0.f;
    for (int j = 0; j < 8; ++j) den += __expf(s_lg[j] - m);
    float v = 0.f;
    if (lane < 8) v = __expf(s_lg[lane] - m) / den;
    else if (lane == 8) v = 1.f;
    gf_out[e * 12 + lane] = v;
  }
  row[lane]       = f2bf(s_nc[lane]);
  row[64 + lane]  = f2bf(s_ef[lane]);
  row[128 + lane] = f2bf(s_nn[lane]);
  if (lane < 48) row[336 + lane] = 0;
  if (lane < 32) { row[672 + lane] = 0; row[800 + lane] = 0; }
#pragma unroll
  for (int it = 0; it < 5; ++it) {
    int q = lane + it * 64;
    if (q < 288) {
      int i = q / 96, c = q - i * 96;
      const float* src = (c < 32) ? s_nc : (c < 64) ? s_ef : s_nn;
      int base = 64 + (c & 31) * 3;
      float v = s_d1[i * 3] * src[base] + s_d1[i * 3 + 1] * src[base + 1] + s_d1[i * 3 + 2] * src[base + 2];
      int dst = (i == 0) ? 528 : (i == 1) ? 192 : 384;
      row[dst + c] = f2bf(v);
    }
  }
#pragma unroll
  for (int it = 0; it < 4; ++it) {
    int q = lane + it * 64;
    if (q < 240) {
      int i = q / 48, c = q - i * 48;
      const float* src = (c < 16) ? s_nc : (c < 32) ? s_ef : s_nn;
      int base = 160 + (c & 15) * 5;
      float v = s_d2[i * 5] * src[base] + s_d2[i * 5 + 1] * src[base + 1] +
                s_d2[i * 5 + 2] * src[base + 2] + s_d2[i * 5 + 3] * src[base + 3] +
                s_d2[i * 5 + 4] * src[base + 4];
      int dst = (i == 0) ? 752 : (i == 1) ? 624 : (i == 2) ? 288 : (i == 3) ? 480 : 704;
      row[dst + c] = f2bf(v);
    }
  }
  const uintx4* row4 = (const uintx4*)row;
  uintx4* dst4 = (uintx4*)(f_all + (size_t)e * 832);
#pragma unroll
  for (int it = 0; it < 2; ++it) {
    int q = lane + it * 64;
    if (q < 104) dst4[q] = row4[q];
  }
}

// ------- bf16 MFMA GEMM body (device) -------
// NGRP>1: A-fragments cached in registers; LDS holds B only (3-buf, counted vmcnt).
// NGRP==1: classic A+B double-buffered DMA staging.
template <int WAVES, int BM, int KZP, int SPG2, int NGRP, int NCOL, int FOFF, int ASTRIDE,
          bool HASBIAS, int EPI>
__device__ __forceinline__ void gemm_dev(
    int bid, char* sm,
    const ushort* __restrict__ A, const ushort* __restrict__ Bt,
    const float* __restrict__ gf, const float* __restrict__ bias,
    ushort* __restrict__ outb, int ob_stride, int ob_off,
    ushort* __restrict__ outb2) {
  constexpr int T = WAVES * 64;
  constexpr int WRS = WAVES / 2;
  constexpr int RPW = BM / WRS;
  constexpr int MI = RPW / 16;
  constexpr int NFW = NCOL / 32;
  constexpr int A_BYTES = BM * 128;
  constexpr int B_BYTES = NCOL * 128;
  constexpr int NT2 = KZP / 64;
  constexpr int AI = (BM * 8) / T;
  constexpr int NB = NCOL * 8;
  constexpr int BI = (NB + T - 1) / T;
  static_assert(NCOL % 32 == 0 && KZP % 64 == 0 && RPW % 16 == 0 && (BM * 8) % T == 0, "geom");
  const int tid = threadIdx.x;
  const int lane = tid & 63, wid = tid >> 6;
  const int wr = wid >> 1, wc = wid & 1;
  const int g16 = lane >> 4;
  const int lane15 = lane & 15;
  const int e0 = bid * BM;
  const f32x4 vzero = {0.f, 0.f, 0.f, 0.f};

  const char* bSrc[BI];
#pragma unroll
  for (int it = 0; it < BI; ++it) {
    int q = tid + it * T;
    if (q < NB) {
      int c = q >> 3, ch = (q & 7) ^ (c & 7);
      bSrc[it] = (const char*)(Bt + (size_t)c * KZP) + ch * 16;
    } else bSrc[it] = nullptr;
  }

  f32x4 accS[MI][NFW];
#pragma unroll
  for (int mi = 0; mi < MI; ++mi)
#pragma unroll
    for (int n = 0; n < NFW; ++n) accS[mi][n] = vzero;

  if constexpr (NGRP > 1) {
    char* b_lds = sm;
    f32x4 accC[MI][NFW];
#pragma unroll
    for (int mi = 0; mi < MI; ++mi)
#pragma unroll
      for (int n = 0; n < NFW; ++n) accC[mi][n] = vzero;

    float gfr[MI][4];
    auto gf_pref = [&](int gx) {
#pragma unroll
      for (int mi = 0; mi < MI; ++mi)
#pragma unroll
        for (int j = 0; j < 4; ++j)
          gfr[mi][j] = gf[(size_t)(e0 + wr * RPW + mi * 16 + g16 * 4 + j) * 12 + gx];
    };
    gf_pref(0);

    bf16x8 afr[SPG2][MI][2];
#pragma unroll
    for (int wi = 0; wi < SPG2; ++wi)
#pragma unroll
      for (int mi = 0; mi < MI; ++mi)
#pragma unroll
        for (int s = 0; s < 2; ++s)
          afr[wi][mi][s] = *(const bf16x8*)(
              A + (size_t)(e0 + wr * RPW + mi * 16 + lane15) * ASTRIDE + FOFF +
              wi * 64 + s * 32 + g16 * 8);

    auto stageB = [&](int t2, int buf) {
#pragma unroll
      for (int it = 0; it < BI; ++it) {
        int q = tid + it * T;
        if (q < NB)
          gload16(bSrc[it] + (size_t)t2 * 128, b_lds + buf * B_BYTES + (tid - lane + it * T) * 16);
      }
    };

    // per-wave load count per batch (wave-uniform): FULLI or FULLI+1
    constexpr int FULLI = NB / T;
    constexpr int PARTW = (NB % T) / 64;  // waves [0,PARTW) carry one extra load
    auto wait_tail = [&](bool issued) {
      if (!issued) { wait_vm<0>(); return; }
      if constexpr ((NB % T) == 0) {
        wait_vm<FULLI>();
      } else {
        if (wid < PARTW) wait_vm<FULLI + 1>(); else wait_vm<FULLI>();
      }
    };

    // prologue: 2-deep prefetch, then wait batch0 (allow batch1 in flight)
    stageB(0, 0);
    stageB(1, 1);
    wait_tail(true);
    __builtin_amdgcn_s_barrier();
    asm volatile("" ::: "memory");

    for (int g = 0; g < NGRP; ++g) {
#pragma unroll
      for (int wi = 0; wi < SPG2; ++wi) {
        int t2 = g * SPG2 + wi;
        bool issue = (t2 + 2) < NT2;
        if (issue) stageB(t2 + 2, (t2 + 2) % 3);
        const char* bL = b_lds + (t2 % 3) * B_BYTES;
#pragma unroll
        for (int s = 0; s < 2; ++s) {
#pragma unroll
          for (int n = 0; n < NFW; ++n) {
            int cB = (wc * NFW + n) * 16 + lane15;
            int slot = (s * 4 + g16) ^ (cB & 7);
            bf16x8 b = *(const bf16x8*)(bL + cB * 128 + slot * 16);
#pragma unroll
            for (int mi = 0; mi < MI; ++mi)
              accC[mi][n] = __builtin_amdgcn_mfma_f32_16x16x32_bf16(afr[wi][mi][s], b, accC[mi][n], 0, 0, 0);
          }
        }
        if (wi == SPG2 - 1) {
#pragma unroll
          for (int mi = 0; mi < MI; ++mi)
#pragma unroll
            for (int n = 0; n < NFW; ++n) {
#pragma unroll
              for (int j = 0; j < 4; ++j) accS[mi][n][j] += gfr[mi][j] * accC[mi][n][j];
              accC[mi][n] = vzero;
            }
          if (g + 1 < NGRP) gf_pref(g + 1);
        }
        // counted wait: batches <= t2+1 complete; batch t2+2 stays in flight
        wait_tail(issue);
        __builtin_amdgcn_s_barrier();
        asm volatile("" ::: "memory");
      }
    }
  } else {
    char* a_lds = sm;
    char* b_lds = sm + 2 * A_BYTES;
    const char* aSrc[AI];
#pragma unroll
    for (int it = 0; it < AI; ++it) {
      int q = tid + it * T;
      int r = q >> 3, ch = (q & 7) ^ (r & 7);
      aSrc[it] = (const char*)(A + (size_t)(e0 + r) * ASTRIDE + FOFF) + ch * 16;
    }
    auto stage = [&](int t2, int buf) {
#pragma unroll
      for (int it = 0; it < AI; ++it)
        gload16(aSrc[it] + t2 * 128, a_lds + buf * A_BYTES + (tid - lane + it * T) * 16);
#pragma unroll
      for (int it = 0; it < BI; ++it) {
        int q = tid + it * T;
        if (q < NB)
          gload16(bSrc[it] + t2 * 128, b_lds + buf * B_BYTES + (tid - lane + it * T) * 16);
      }
    };
    stage(0, 0);
    __syncthreads();
    int cur = 0;
    for (int t2 = 0; t2 < NT2; ++t2) {
      if (t2 + 1 < NT2) stage(t2 + 1, cur ^ 1);
      const char* aL = a_lds + cur * A_BYTES;
      const char* bL = b_lds + cur * B_BYTES;
#pragma unroll
      for (int s = 0; s < 2; ++s) {
        bf16x8 a[MI];
#pragma unroll
        for (int mi = 0; mi < MI; ++mi) {
          int rA = wr * RPW + mi * 16 + lane15;
          int slot = (s * 4 + g16) ^ (rA & 7);
          a[mi] = *(const bf16x8*)(aL + rA * 128 + slot * 16);
        }
#pragma unroll
        for (int n = 0; n < NFW; ++n) {
          int cB = (wc * NFW + n) * 16 + lane15;
          int slot = (s * 4 + g16) ^ (cB & 7);
          bf16x8 b = *(const bf16x8*)(bL + cB * 128 + slot * 16);
#pragma unroll
          for (int mi = 0; mi < MI; ++mi)
            accS[mi][n] = __builtin_amdgcn_mfma_f32_16x16x32_bf16(a[mi], b, accS[mi][n], 0, 0, 0);
        }
      }
      __syncthreads();
      cur ^= 1;
    }
  }

#pragma unroll
  for (int mi = 0; mi < MI; ++mi) {
    const int row0 = wr * RPW + mi * 16 + g16 * 4;
#pragma unroll
    for (int n = 0; n < NFW; ++n) {
      const int c = (wc * NFW + n) * 16 + lane15;
      float bv = 0.f;
      if constexpr (HASBIAS) bv = bias[c];
#pragma unroll
      for (int j = 0; j < 4; ++j) {
        float v = accS[mi][n][j] + bv;
        const int er = e0 + row0 + j;
        if constexpr (EPI == 1) v = v / (1.f + __expf(-v));
        outb[(size_t)er * ob_stride + ob_off + c] = f2bf(v);
        if constexpr (EPI == 2) {
          if ((wc * NFW + n) * 16 < 64)
            outb2[(size_t)er * 256 + c] = f2bf(v / (1.f + __expf(-v)));
        }
      }
    }
  }
}

// ---- merged MoE GEMMs: one launch, 512-thread blocks (R17 geometry + 3-buf counted vmcnt) ----
struct MoeArgs {
  const ushort *f_all, *B0t, *B1t, *B2t;
  const float* gfb;
  ushort *moeout, *m2in;
};
__global__ __launch_bounds__(512) void k_moe(MoeArgs a) {
  __shared__ char sm[3 * 160 * 128 + 16];  // max B triple-buffer (moe0)
  int bid = blockIdx.x;
  if (bid < 512) {
    gemm_dev<8, 128, 3456, 6, 9, 160, 0, 832, false, 2>(
        bid, sm, a.f_all, a.B0t, a.gfb, nullptr, a.moeout, 288, 0, a.m2in);
  } else if (bid < 1024) {
    gemm_dev<8, 128, 2880, 5, 9, 96, 384, 832, false, 0>(
        bid - 512, sm, a.f_all, a.B1t, a.gfb, nullptr, a.moeout, 288, 160, nullptr);
  } else {
    gemm_dev<8, 128, 1152, 2, 9, 32, 704, 832, false, 0>(
        bid - 1024, sm, a.f_all, a.B2t, a.gfb, nullptr, a.moeout, 288, 256, nullptr);
  }
}

// ---- merged small GEMMs ----
struct Small3Args {
  const ushort *latbf, *Wet, *m2in, *Ttb, *P0t;
  const float* b0;
  ushort *wbuf, *tbuf, *m1in;
};
__global__ __launch_bounds__(256) void k_small3(Small3Args a) {
  __shared__ char sm[49168];
  int bid = blockIdx.x;
  if (bid < 1024) {
    gemm_dev<4, 64, 128, 1, 1, 128, 0, 128, false, 0>(
        bid, sm, a.latbf, a.Wet, nullptr, nullptr, a.wbuf, 128, 0, nullptr);
  } else if (bid < 2048) {
    gemm_dev<4, 64, 128, 1, 1, 128, 128, 256, false, 0>(
        bid - 1024, sm, a.m2in, a.Ttb, nullptr, nullptr, a.tbuf, 128, 0, nullptr);
  } else {
    gemm_dev<4, 64, 64, 1, 1, 64, 0, 256, true, 0>(
        bid - 2048, sm, a.m2in, a.P0t, nullptr, a.b0, a.m1in, 192, 128, nullptr);
  }
}

// ---------------- fused 6-layer MLP: 32 edges/block, X in LDS, W double-buffered ----------
struct MlpArgs {
  const ushort *m1in, *m2in, *Wt1, *Wt2, *Wt3, *Wt4, *Wt5, *Wt6;
  const float *b1, *b2, *b3, *b4, *b5, *b6;
  const int* act;
  const float *cutg, *latg;
  float* out_lat;
};
__global__ __launch_bounds__(256) void k_mlp(MlpArgs A) {
  __shared__ char sm[61440];
  char* Xa = sm;
  char* Xb = sm + 12288;
  char* Xe = sm + 20480;
  char* W0 = sm + 28672;
  char* W1 = sm + 45056;
  const int tid = threadIdx.x;
  const int lane = tid & 63, w = tid >> 6;
  const int wr = w >> 1, wc = w & 1;
  const int lane15 = lane & 15, g16 = lane >> 4;
  const int e32 = blockIdx.x * 32;
  const f32x4 vzero = {0.f, 0.f, 0.f, 0.f};

  auto stage_w = [&](const ushort* Wt, int K2, int t2, char* dst) {
#pragma unroll
    for (int it = 0; it < 4; ++it) {
      int q = tid + it * 256;
      int c = q >> 3, ch = (q & 7) ^ (c & 7);
      gload16((const char*)Wt + (size_t)c * K2 + t2 * 128 + ch * 16,
              dst + (w + it * 4) * 1024);
    }
  };
  {
#pragma unroll
    for (int it = 0; it < 3; ++it) {
      int q = tid + it * 256;
      int r = q / 24, c24 = q - r * 24;
      int t2 = c24 >> 3, ch = (c24 & 7) ^ (r & 7);
      gload16((const char*)A.m1in + (size_t)(e32 + r) * 384 + t2 * 128 + ch * 16,
              Xa + (w + it * 4) * 1024);
    }
#pragma unroll
    for (int it = 0; it < 2; ++it) {
      int q = tid + it * 256;
      int r = q >> 4, c16 = q & 15;
      int t2 = c16 >> 3, ch = (c16 & 7) ^ (r & 7);
      gload16((const char*)A.m2in + (size_t)(e32 + r) * 512 + 256 + t2 * 128 + ch * 16,
              Xe + (w + it * 4) * 1024);
    }
  }
  stage_w(A.Wt1, 384, 0, W0);
  __syncthreads();

  f32x4 acc[4];
#pragma unroll
  for (int n = 0; n < 4; ++n) acc[n] = vzero;

  auto compute = [&](const char* xin, int xstride, int t2loc, const char* wl) {
#pragma unroll
    for (int s = 0; s < 2; ++s) {
      int row = wr * 16 + lane15;
      bf16x8 a = *(const bf16x8*)(xin + row * xstride + t2loc * 128 + (((s * 4 + g16) ^ (row & 7)) << 4));
#pragma unroll
      for (int n = 0; n < 4; ++n) {
        int cB = wc * 64 + n * 16 + lane15;
        bf16x8 b = *(const bf16x8*)(wl + cB * 128 + (((s * 4 + g16) ^ (cB & 7)) << 4));
        acc[n] = __builtin_amdgcn_mfma_f32_16x16x32_bf16(a, b, acc[n], 0, 0, 0);
      }
    }
  };
  auto epi_x = [&](const float* bias, char* xout, int xstride, bool dosilu) {
#pragma unroll
    for (int n = 0; n < 4; ++n) {
      int c = wc * 64 + n * 16 + lane15;
      float bv = bias[c];
      int ch = (n * 16 + lane15) >> 3;
#pragma unroll
      for (int j = 0; j < 4; ++j) {
        int row = wr * 16 + g16 * 4 + j;
        float v = acc[n][j] + bv;
        if (dosilu) v = v / (1.f + __expf(-v));
        *(ushort*)(xout + row * xstride + wc * 128 + ((ch ^ (row & 7)) << 4) + ((lane15 & 7) << 1)) = f2bf(v);
      }
      acc[n] = vzero;
    }
  };

  stage_w(A.Wt1, 384, 1, W1); compute(Xa, 384, 0, W0); __syncthreads();
  stage_w(A.Wt1, 384, 2, W0); compute(Xa, 384, 1, W1); __syncthreads();
  stage_w(A.Wt2, 256, 0, W1); compute(Xa, 384, 2, W0); epi_x(A.b1, Xb, 256, true); __syncthreads();
  stage_w(A.Wt2, 256, 1, W0); compute(Xb, 256, 0, W1); __syncthreads();
  stage_w(A.Wt3, 256, 0, W1); compute(Xb, 256, 1, W0); epi_x(A.b2, Xa, 384, true); __syncthreads();
  stage_w(A.Wt3, 256, 1, W0); compute(Xa, 384, 0, W1); __syncthreads();
  stage_w(A.Wt4, 512, 0, W1); compute(Xa, 384, 1, W0); epi_x(A.b3, Xb, 256, false); __syncthreads();
  stage_w(A.Wt4, 512, 1, W0); compute(Xb, 256, 0, W1); __syncthreads();
  stage_w(A.Wt4, 512, 2, W1); compute(Xb, 256, 1, W0); __syncthreads();
  stage_w(A.Wt4, 512, 3, W0); compute(Xe, 256, 0, W1); __syncthreads();
  stage_w(A.Wt5, 256, 0, W1); compute(Xe, 256, 1, W0); epi_x(A.b4, Xa, 384, true); __syncthreads();
  stage_w(A.Wt5, 256, 1, W0); compute(Xa, 384, 0, W1); __syncthreads();
  stage_w(A.Wt6, 256, 0, W1); compute(Xa, 384, 1, W0); epi_x(A.b5, Xb, 256, true); __syncthreads();
  stage_w(A.Wt6, 256, 1, W0); compute(Xb, 256, 0, W1); __syncthreads();
  compute(Xb, 256, 1, W0);
#pragma unroll
  for (int n = 0; n < 4; ++n) {
    int c = wc * 64 + n * 16 + lane15;
    float bv = A.b6[c];
#pragma unroll
    for (int j = 0; j < 4; ++j) {
      int row = wr * 16 + g16 * 4 + j;
      int er = e32 + row;
      int ae = A.act[er];
      float v = acc[n][j] + bv;
      A.out_lat[(size_t)ae * 128 + c] = C_NEW * A.cutg[ae] * v + C_OLD * A.latg[(size_t)ae * 128 + c];
    }
  }
}

// ------ post-MoE + final combine: wave-per-edge, 8 edges/block; P-mixes via 3 MFMAs ------
__global__ __launch_bounds__(512) void k_postf(
    const ushort* __restrict__ moeout,
    const float* __restrict__ D1g, const float* __restrict__ D2g,
    const float* __restrict__ latg, const int* __restrict__ act,
    const float* __restrict__ P1, const float* __restrict__ P2,
    const ushort* __restrict__ wbuf, const float* __restrict__ beg,
    const float* __restrict__ lng, const float* __restrict__ lnb,
    const ushort* __restrict__ tbufp, const float* __restrict__ efg,
    ushort* __restrict__ m1in, float* __restrict__ out_edge) {
  __shared__ float SM[1136 + 8 * 920];
  ushort* Btab = (ushort*)SM;
  float* be_s = SM + 768;
  float* lng_s = SM + 880;
  float* lnb_s = SM + 1008;
  const int t = threadIdx.x;
  const int w = t >> 6, lane = t & 63;
  float* Wp = SM + 1136 + w * 920;
  float* o   = Wp;
  float* row = Wp + 224;
  float* sg  = Wp + 464;
  float* d1  = Wp + 512;
  float* d2  = Wp + 524;
  ushort* wvh = (ushort*)(Wp + 552);
  ushort* tvh = (ushort*)(Wp + 608);
  ushort* tile = (ushort*)(Wp + 664);
  const int e = blockIdx.x * 8 + w;
  const int ae = act[e];
  const f32x4 vzero = {0.f, 0.f, 0.f, 0.f};

  float ef[4];
  ef[0] = efg[(size_t)e * 240 + lane];
  ef[1] = efg[(size_t)e * 240 + 64 + lane];
  ef[2] = efg[(size_t)e * 240 + 128 + lane];
  ef[3] = (lane < 48) ? efg[(size_t)e * 240 + 192 + lane] : 0.f;
  float2v ll = ((const float2v*)(latg + (size_t)ae * 128))[lane];

  if (lane < 28) {
    uintx4 raw = *(const uintx4*)(moeout + (size_t)e * 288 + 64 + lane * 8);
    float* dst = o + lane * 8;
#pragma unroll
    for (int j = 0; j < 4; ++j) {
      uint u = raw[j];
      dst[2 * j] = bf2f((ushort)(u & 0xFFFF));
      dst[2 * j + 1] = bf2f((ushort)(u >> 16));
    }
  }
  if (lane < 14) {
    *(uintx4*)((char*)wvh + lane * 16) = *(const uintx4*)(wbuf + (size_t)e * 128 + lane * 8);
    *(uintx4*)((char*)tvh + lane * 16) = *(const uintx4*)(tbufp + (size_t)e * 128 + lane * 8);
  }
  if (lane < 8) {
    uintx4 raw = *(const uintx4*)(m1in + (size_t)e * 192 + 128 + lane * 8);
    float* dst = row + lane * 8;
#pragma unroll
    for (int j = 0; j < 4; ++j) {
      uint u = raw[j];
      dst[2 * j] = bf2f((ushort)(u & 0xFFFF));
      dst[2 * j + 1] = bf2f((ushort)(u >> 16));
    }
  }
  if (lane < 9)  d1[lane] = D1g[(size_t)e * 9 + lane];
  if (lane < 25) d2[lane] = D2g[(size_t)e * 25 + lane];
  if (lane < 48) sg[lane] = 1.f / (1.f + __expf(-o[lane]));

#pragma unroll
  for (int i = 0; i < 3; ++i) {
    int q = t + i * 512;
    int tbl = q >> 9, idx = q & 511;
    int d = idx >> 5, c = idx & 31;
    float v;
    if (tbl == 0) v = P1[c * 32 + d];
    else if (tbl == 1) v = P1[c * 32 + 16 + d];
    else v = (c < 16) ? P2[c * 16 + d] : 0.f;
    Btab[tbl * 512 + d * 32 + (((c >> 3) ^ (d & 3)) << 3) + (c & 7)] = f2bf(v);
  }
  if (t < 368) {
    if (t < 112) be_s[t] = beg[t];
    else if (t < 240) lng_s[t - 112] = lng[t - 112];
    else lnb_s[t - 240] = lnb[t - 240];
  }

  float sum = ll[0] + ll[1];
  float sq = ll[0] * ll[0] + ll[1] * ll[1];
#pragma unroll
  for (int m = 32; m > 0; m >>= 1) {
    sum += __shfl_xor(sum, m);
    sq += __shfl_xor(sq, m);
  }
  const float mu = sum * (1.f / 128.f);
  const float rs = rsqrtf(sq * (1.f / 128.f) - mu * mu + 1e-5f);

  __syncthreads();

  {
    int i = 2 * lane;
    float l0 = (ll[0] - mu) * rs * lng_s[i] + lnb_s[i];
    float l1 = (ll[1] - mu) * rs * lng_s[i + 1] + lnb_s[i + 1];
    ((uint*)m1in)[(size_t)e * 96 + lane] = (uint)f2bf(l0) | ((uint)f2bf(l1) << 16);
  }
#pragma unroll
  for (int rr = 0; rr < 2; ++rr) {
    int r = lane + rr * 64;
    if (r < 96) {
      int m = r >> 5, c = r & 31;
      float v = d1[m] * o[144 + c] + d1[3 + m] * o[48 + c] + d1[6 + m] * o[96 + c];
      tile[m * 32 + (((c >> 3) ^ (m & 3)) << 3) + (c & 7)] = f2bf(v * sg[c]);
    }
  }
#pragma unroll
  for (int rr = 0; rr < 3; ++rr) {
    int r = lane + rr * 64;
    if (r < 160) {
      int rw = 3 + (r >> 5), c = r & 31;
      ushort hv = 0;
      if (c < 16) {
        int m = rw - 3;
        float v = d2[m] * o[208 + c] + d2[5 + m] * o[176 + c] + d2[10 + m] * o[80 + c] +
                  d2[15 + m] * o[128 + c] + d2[20 + m] * o[192 + c];
        hv = f2bf(v * sg[32 + c]);
      }
      tile[rw * 32 + (((c >> 3) ^ (rw & 3)) << 3) + (c & 7)] = hv;
    }
  }
  {
    const int r15 = lane & 15, g = lane >> 4;
    const int fslot = (g ^ (r15 & 3)) << 3;
    bf16x8 afr = *(const bf16x8*)(tile + r15 * 32 + fslot);
    bf16x8 b1a = *(const bf16x8*)(Btab + r15 * 32 + fslot);
    bf16x8 b1b = *(const bf16x8*)(Btab + 512 + r15 * 32 + fslot);
    bf16x8 b2p = *(const bf16x8*)(Btab + 1024 + r15 * 32 + fslot);
    f32x4 v1a = __builtin_amdgcn_mfma_f32_16x16x32_bf16(afr, b1a, vzero, 0, 0, 0);
    f32x4 v1b = __builtin_amdgcn_mfma_f32_16x16x32_bf16(afr, b1b, vzero, 0, 0, 0);
    f32x4 v2r = __builtin_amdgcn_mfma_f32_16x16x32_bf16(afr, b2p, vzero, 0, 0, 0);
    if (g == 0) {
      float s1 = bf2f(wvh[64 + r15]) + be_s[64 + r15];
      row[64 + r15 * 3 + 0] = v1a[0] * s1;
      row[64 + r15 * 3 + 1] = v1a[1] * s1;
      row[64 + r15 * 3 + 2] = v1a[2] * s1;
      float s2 = bf2f(wvh[80 + r15]) + be_s[80 + r15];
      row[64 + (16 + r15) * 3 + 0] = v1b[0] * s2;
      row[64 + (16 + r15) * 3 + 1] = v1b[1] * s2;
      row[64 + (16 + r15) * 3 + 2] = v1b[2] * s2;
      float s3 = bf2f(wvh[96 + r15]) + be_s[96 + r15];
      row[160 + r15 * 5 + 0] = v2r[3] * s3;
    } else if (g == 1) {
      float s3 = bf2f(wvh[96 + r15]) + be_s[96 + r15];
      row[160 + r15 * 5 + 1] = v2r[0] * s3;
      row[160 + r15 * 5 + 2] = v2r[1] * s3;
      row[160 + r15 * 5 + 3] = v2r[2] * s3;
      row[160 + r15 * 5 + 4] = v2r[3] * s3;
    }
  }
  row[lane] = row[lane] * (bf2f(wvh[lane]) + be_s[lane]);
#pragma unroll
  for (int r = 0; r < 4; ++r) {
    int d = lane + r * 64;
    if (r < 3 || lane < 48) {
      float v = C_OLD * ef[r] + C_NEW * row[d];
      int ti = (d < 64) ? d : (d < 160) ? 64 + (d - 64) / 3 : 96 + (d - 160) / 5;
      float f = bf2f(tvh[ti]) * T_SCALE;
      out_edge[(size_t)e * 240 + d] = v * (1.f + f);
    }
  }
}

extern "C" void kernel_launch(void* const* d_in, const int* in_sizes, int n_in,
                              void* d_out, int out_size, void* d_ws, size_t ws_size,
                              hipStream_t stream) {
  const float* latents = (const float*)d_in[0];
  const float* node_f  = (const float*)d_in[1];
  const float* edge_f  = (const float*)d_in[3];
  const float* cutoff  = (const float*)d_in[5];
  const float* eoh     = (const float*)d_in[6];
  const float* D1      = (const float*)d_in[7];
  const float* D2      = (const float*)d_in[8];
  const float* mg      = (const float*)d_in[9];
  const int*   eidx    = (const int*)d_in[10];
  const int*   act     = (const int*)d_in[11];
  const float* Wg      = (const float*)d_in[12];
  const float* W0      = (const float*)d_in[13];
  const float* W1r     = (const float*)d_in[14];
  const float* W1i     = (const float*)d_in[15];
  const float* W2r     = (const float*)d_in[16];
  const float* W2i     = (const float*)d_in[17];
  const float* P0      = (const float*)d_in[18];
  const float* b0      = (const float*)d_in[19];
  const float* P1      = (const float*)d_in[20];
  const float* P2      = (const float*)d_in[21];
  const float* We      = (const float*)d_in[22];
  const float* be      = (const float*)d_in[23];
  const float* lng     = (const float*)d_in[24];
  const float* lnb     = (const float*)d_in[25];
  const float* M1W0_   = (const float*)d_in[26];
  const float* M1b0_   = (const float*)d_in[27];
  const float* M1W1_   = (const float*)d_in[28];
  const float* M1b1_   = (const float*)d_in[29];
  const float* M1W2_   = (const float*)d_in[30];
  const float* M1b2_   = (const float*)d_in[31];
  const float* M2W0_   = (const float*)d_in[32];
  const float* M2b0_   = (const float*)d_in[33];
  const float* M2W1_   = (const float*)d_in[34];
  const float* M2b1_   = (const float*)d_in[35];
  const float* M2W2_   = (const float*)d_in[36];
  const float* M2b2_   = (const float*)d_in[37];
  const float* T0      = (const float*)d_in[38];
  const float* T1      = (const float*)d_in[39];
  const float* T2      = (const float*)d_in[40];

  float* out_edge = (float*)d_out;
  float* out_lat  = out_edge + (size_t)EDGES * 240;
  float* out_d1   = out_lat + (size_t)EDGES * 128;
  float* out_d2   = out_d1 + (size_t)EDGES * 9;

  char* ws = (char*)d_ws;
  size_t off = 0;
  auto alloc = [&](size_t bytes) -> char* {
    char* p = ws + off;
    off += (bytes + 255) & ~size_t(255);
    return p;
  };
  ushort* f_all  = (ushort*)alloc((size_t)EDGES * 832 * 2);
  float*  gfb    = (float*) alloc((size_t)EDGES * 12 * 4);
  ushort* moeout = (ushort*)alloc((size_t)EDGES * 288 * 2);
  ushort* m2in   = (ushort*)alloc((size_t)EDGES * 256 * 2);
  ushort* latbf  = (ushort*)alloc((size_t)EDGES * 128 * 2);
  ushort* wbuf   = (ushort*)alloc((size_t)EDGES * 128 * 2);
  ushort* B0t    = (ushort*)alloc(160 * 3456 * 2);
  ushort* B1t    = (ushort*)alloc(96 * 2880 * 2);
  ushort* B2t    = (ushort*)alloc(32 * 1152 * 2);
  ushort* Wt1    = (ushort*)alloc(128 * 192 * 2);
  ushort* Wt2    = (ushort*)alloc(128 * 128 * 2);
  ushort* Wt3    = (ushort*)alloc(128 * 128 * 2);
  ushort* Wt4    = (ushort*)alloc(128 * 256 * 2);
  ushort* Wt5    = (ushort*)alloc(128 * 128 * 2);
  ushort* Wt6    = (ushort*)alloc(128 * 128 * 2);
  ushort* Wet    = (ushort*)alloc(128 * 128 * 2);
  ushort* Ttb    = (ushort*)alloc(128 * 128 * 2);
  ushort* P0t    = (ushort*)alloc(64 * 64 * 2);

  ushort* m1in = f_all;   // E*192 overlay (dead after MoE GEMMs)
  ushort* tbuf = latbf;   // reused after We-GEMM

  if (ws_size < off) return;

  // merged front: pack (blocks [0,4008)) + prep w/ D1,D2 passthrough (blocks [4008,20392))
  PackArgs pk = {W0, W1r, W1i, W2r, W2i,
                 M1W0_, M1W1_, M1W2_, M2W0_, M2W1_, M2W2_, We, T0, T1, T2, P0,
                 B0t, B1t, B2t,
                 Wt1, Wt2, Wt3, Wt4, Wt5, Wt6, Wet, Ttb, P0t};
  k_front<<<PACK_BLOCKS + EDGES / 4, 256, 0, stream>>>(
      pk, node_f, edge_f, D1, D2, mg, Wg, latents, eoh, eidx, act,
      f_all, gfb, latbf, m2in, out_d1, out_d2);

  // merged MoE GEMMs: BM=128, 8 waves/block, 3-buf counted-vmcnt pipeline
  MoeArgs mo = {f_all, B0t, B1t, B2t, gfb, moeout, m2in};
  k_moe<<<1536, 512, 0, stream>>>(mo);

  // merged small GEMMs: lat@We | eoh@T^T | scs@P0+b0 in one launch
  Small3Args s3 = {latbf, Wet, m2in, Ttb, P0t, b0, wbuf, tbuf, m1in};
  k_small3<<<3072, 256, 0, stream>>>(s3);

  // fused post + final combine (wave-per-edge, 8 edges/block, MFMA P-mixes)
  k_postf<<<EDGES / 8, 512, 0, stream>>>(moeout, D1, D2, latents, act, P1, P2,
                                         wbuf, be, lng, lnb, tbuf, edge_f, m1in, out_edge);

  // fused 6-layer MLP chain (final layer fuses latent update into out_lat)
  MlpArgs ma = {m1in, m2in, Wt1, Wt2, Wt3, Wt4, Wt5, Wt6,
                M1b0_, M1b1_, M1b2_, M2b0_, M2b1_, M2b2_,
                act, cutoff, latents, out_lat};
  k_mlp<<<EDGES / 32, 256, 0, stream>>>(ma);
}

// Round 25
// 406.379 us; speedup vs baseline: 1.0768x; 1.0070x over previous
//
#include <hip/hip_runtime.h>
#include <hip/hip_bf16.h>
#include <stdint.h>

#define EDGES 65536

typedef unsigned int uint;
typedef unsigned short ushort;
using bf16x8 = __attribute__((ext_vector_type(8))) __bf16;
using f32x4  = __attribute__((ext_vector_type(4))) float;
using uintx4 = __attribute__((ext_vector_type(4))) uint;
using float4v = __attribute__((ext_vector_type(4))) float;
using float2v = __attribute__((ext_vector_type(2))) float;

#define C_OLD 0.8944271909999159f
#define C_NEW 0.4472135954999579f
#define T_SCALE 0.08838834764831845f

__device__ __forceinline__ ushort f2bf(float f) {
  uint x = __builtin_bit_cast(uint, f);
  uint r = x + 0x7FFFu + ((x >> 16) & 1u);
  return (ushort)(r >> 16);
}
__device__ __forceinline__ float bf2f(ushort u) {
  uint x = (uint)u << 16;
  return __builtin_bit_cast(float, x);
}
__device__ __forceinline__ void gload16(const void* g, void* l) {
  __builtin_amdgcn_global_load_lds(
      (const __attribute__((address_space(1))) void*)g,
      (__attribute__((address_space(3))) void*)l, 16, 0, 0);
}
// counted-vmcnt wait (immediate must be a literal per variant)
template <int N> __device__ __forceinline__ void wait_vm() {
  if constexpr (N <= 0) asm volatile("s_waitcnt vmcnt(0)" ::: "memory");
  else if constexpr (N == 1) asm volatile("s_waitcnt vmcnt(1)" ::: "memory");
  else if constexpr (N == 2) asm volatile("s_waitcnt vmcnt(2)" ::: "memory");
  else if constexpr (N == 3) asm volatile("s_waitcnt vmcnt(3)" ::: "memory");
  else asm volatile("s_waitcnt vmcnt(4)" ::: "memory");
}
__device__ __forceinline__ void bar_lgkm() {
  asm volatile("s_waitcnt lgkmcnt(0)" ::: "memory");
  __builtin_amdgcn_s_barrier();
  asm volatile("" ::: "memory");
}

// ---------------- merged front kernel: weight pack + prep (+ D1/D2 passthrough) ----------------
struct PackArgs {
  const float *W0, *W1r, *W1i, *W2r, *W2i;
  const float *s0, *s1, *s2, *s3, *s4, *s5, *we, *t0, *t1, *t2, *p0;
  ushort *B0, *B1, *B2;
  ushort *d0, *d1, *d2, *d3, *d4, *d5, *dwe, *dtt, *dp0;
};
#define PACK_BLOCKS 4008
__global__ __launch_bounds__(256) void k_front(
    PackArgs p,
    const float* __restrict__ node_f, const float* __restrict__ edge_f,
    const float* __restrict__ D1g, const float* __restrict__ D2g,
    const float* __restrict__ mg_g, const float* __restrict__ Wg,
    const float* __restrict__ latg, const float* __restrict__ eohg,
    const int* __restrict__ eidx, const int* __restrict__ act,
    ushort* __restrict__ f_all, float* __restrict__ gf_out,
    ushort* __restrict__ lat_bf, ushort* __restrict__ mlp2_in,
    float* __restrict__ out_d1, float* __restrict__ out_d2) {
  __shared__ float sh[4][1244];
  int bid = blockIdx.x;
  if (bid < PACK_BLOCKS) {
    // ---------- pack branch ----------
    if (bid < 2160) {
      int idx = bid * 256 + threadIdx.x;
      if (idx >= 160 * 3456) return;
      int o = idx / 3456, kf = idx - o * 3456;
      int k = kf / 384, f = kf - k * 384;
      float v = (f < 336) ? p.W0[k * 53760 + f * 160 + o] : 0.f;
      p.B0[idx] = f2bf(v);
    } else if (bid < 3240) {
      int idx = (bid - 2160) * 256 + threadIdx.x;
      if (idx >= 96 * 2880) return;
      int c = idx / 2880, kf = idx - c * 2880;
      int k = kf / 320, f = kf - k * 320;
      float v = 0.f;
      if (f < 288) {
        if (c < 48) v = (f < 144) ? p.W1r[k * 6912 + f * 48 + c] : -p.W1i[k * 6912 + (f - 144) * 48 + c];
        else        v = (f < 144) ? p.W1i[k * 6912 + f * 48 + (c - 48)] : p.W1r[k * 6912 + (f - 144) * 48 + (c - 48)];
      }
      p.B1[idx] = f2bf(v);
    } else if (bid < 3384) {
      int idx = (bid - 3240) * 256 + threadIdx.x;
      if (idx >= 32 * 1152) return;
      int c = idx / 1152, kf = idx - c * 1152;
      int k = kf / 128, f = kf - k * 128;
      float v = 0.f;
      if (f < 96) {
        if (c < 16) v = (f < 48) ? p.W2r[k * 768 + f * 16 + c] : -p.W2i[k * 768 + (f - 48) * 16 + c];
        else        v = (f < 48) ? p.W2i[k * 768 + f * 16 + (c - 16)] : p.W2r[k * 768 + (f - 48) * 16 + (c - 16)];
      }
      p.B2[idx] = f2bf(v);
    } else {
      int idx = (bid - 3384) * 256 + threadIdx.x;
      if (idx < 24576) {
        int n = idx / 192, k = idx - n * 192;
        p.d0[idx] = f2bf(p.s0[k * 128 + n]);
      } else if (idx < 40960) {
        int q = idx - 24576; int n = q >> 7, k = q & 127;
        p.d1[q] = f2bf(p.s1[k * 128 + n]);
      } else if (idx < 57344) {
        int q = idx - 40960; int n = q >> 7, k = q & 127;
        p.d2[q] = f2bf(p.s2[k * 128 + n]);
      } else if (idx < 90112) {
        int q = idx - 57344; int n = q / 256, k = q - n * 256;
        p.d3[q] = f2bf(p.s3[k * 128 + n]);
      } else if (idx < 106496) {
        int q = idx - 90112; int n = q >> 7, k = q & 127;
        p.d4[q] = f2bf(p.s4[k * 128 + n]);
      } else if (idx < 122880) {
        int q = idx - 106496; int n = q >> 7, k = q & 127;
        p.d5[q] = f2bf(p.s5[k * 128 + n]);
      } else if (idx < 139264) {
        int q = idx - 122880; int n = q >> 7, k = q & 127;
        p.dwe[q] = f2bf((n < 112) ? p.we[k * 112 + n] : 0.f);
      } else if (idx < 155648) {
        int q = idx - 139264; int o = q >> 7, h = q & 127;
        float v = 0.f;
        if (o < 64) v = p.t0[o * 128 + h];
        else if (o < 96) v = p.t1[(o - 64) * 128 + h];
        else if (o < 112) v = p.t2[(o - 96) * 128 + h];
        p.dtt[q] = f2bf(v);
      } else if (idx < 159744) {
        int q = idx - 155648; int n = q >> 6, k = q & 63;
        p.dp0[q] = f2bf(p.p0[k * 64 + n]);
      }
    }
    return;
  }
  // ---------- prep branch (wave-per-edge) ----------
  const int w = threadIdx.x >> 6, lane = threadIdx.x & 63;
  const int e = (bid - PACK_BLOCKS) * 4 + w;
  float* s = sh[w];
  float* s_nc = s;
  float* s_ef = s + 240;
  float* s_nn = s + 480;
  float* s_d1 = s + 720;
  float* s_d2 = s + 729;
  float* s_mg = s + 754;
  float* s_lg = s + 818;
  ushort* row = (ushort*)(s + 828);
  const int ae = act[e];
  const int ec = eidx[ae], en = eidx[EDGES + ae];
  if (lane < 60) {
    ((float4v*)s_nc)[lane] = ((const float4v*)(node_f + (size_t)ec * 240))[lane];
    ((float4v*)s_ef)[lane] = ((const float4v*)(edge_f + (size_t)e * 240))[lane];
    ((float4v*)s_nn)[lane] = ((const float4v*)(node_f + (size_t)en * 240))[lane];
  }
  if (lane < 9)  { float v = D1g[e * 9 + lane];  s_d1[lane] = v; out_d1[(size_t)e * 9 + lane] = v; }
  if (lane < 25) { float v = D2g[e * 25 + lane]; s_d2[lane] = v; out_d2[(size_t)e * 25 + lane] = v; }
  s_mg[lane] = mg_g[e * 64 + lane];
  {
    const float* lp = latg + (size_t)ae * 128;
    float a0 = lp[2 * lane], a1 = lp[2 * lane + 1];
    ((uint*)lat_bf)[(size_t)e * 64 + lane] = (uint)f2bf(a0) | ((uint)f2bf(a1) << 16);
    const float* ep = eohg + (size_t)e * 128;
    a0 = ep[2 * lane]; a1 = ep[2 * lane + 1];
    ((uint*)mlp2_in)[(size_t)e * 128 + 64 + lane] = (uint)f2bf(a0) | ((uint)f2bf(a1) << 16);
  }
  {
    int k = lane & 7, hg = lane >> 3;
    float a = 0.f;
#pragma unroll
    for (int h = 0; h < 8; ++h) a += s_mg[hg * 8 + h] * Wg[(hg * 8 + h) * 8 + k];
    a += __shfl_xor(a, 8);
    a += __shfl_xor(a, 16);
    a += __shfl_xor(a, 32);
    if (lane < 8) s_lg[lane] = a;
  }
  if (lane < 12) {
    float m = s_lg[0];
    for (int j = 1; j < 8; ++j) m = fmaxf(m, s_lg[j]);
    float den = 0.f;
    for (int j = 0; j < 8; ++j) den += __expf(s_lg[j] - m);
    float v = 0.f;
    if (lane < 8) v = __expf(s_lg[lane] - m) / den;
    else if (lane == 8) v = 1.f;
    gf_out[e * 12 + lane] = v;
  }
  row[lane]       = f2bf(s_nc[lane]);
  row[64 + lane]  = f2bf(s_ef[lane]);
  row[128 + lane] = f2bf(s_nn[lane]);
  if (lane < 48) row[336 + lane] = 0;
  if (lane < 32) { row[672 + lane] = 0; row[800 + lane] = 0; }
#pragma unroll
  for (int it = 0; it < 5; ++it) {
    int q = lane + it * 64;
    if (q < 288) {
      int i = q / 96, c = q - i * 96;
      const float* src = (c < 32) ? s_nc : (c < 64) ? s_ef : s_nn;
      int base = 64 + (c & 31) * 3;
      float v = s_d1[i * 3] * src[base] + s_d1[i * 3 + 1] * src[base + 1] + s_d1[i * 3 + 2] * src[base + 2];
      int dst = (i == 0) ? 528 : (i == 1) ? 192 : 384;
      row[dst + c] = f2bf(v);
    }
  }
#pragma unroll
  for (int it = 0; it < 4; ++it) {
    int q = lane + it * 64;
    if (q < 240) {
      int i = q / 48, c = q - i * 48;
      const float* src = (c < 16) ? s_nc : (c < 32) ? s_ef : s_nn;
      int base = 160 + (c & 15) * 5;
      float v = s_d2[i * 5] * src[base] + s_d2[i * 5 + 1] * src[base + 1] +
                s_d2[i * 5 + 2] * src[base + 2] + s_d2[i * 5 + 3] * src[base + 3] +
                s_d2[i * 5 + 4] * src[base + 4];
      int dst = (i == 0) ? 752 : (i == 1) ? 624 : (i == 2) ? 288 : (i == 3) ? 480 : 704;
      row[dst + c] = f2bf(v);
    }
  }
  const uintx4* row4 = (const uintx4*)row;
  uintx4* dst4 = (uintx4*)(f_all + (size_t)e * 832);
#pragma unroll
  for (int it = 0; it < 2; ++it) {
    int q = lane + it * 64;
    if (q < 104) dst4[q] = row4[q];
  }
}

// ------- bf16 MFMA GEMM body (device) -------
// NGRP>1: A-fragments cached in registers; LDS holds B only (3-buf, counted vmcnt).
// NGRP==1: classic A+B double-buffered DMA staging.
template <int WAVES, int BM, int KZP, int SPG2, int NGRP, int NCOL, int FOFF, int ASTRIDE,
          bool HASBIAS, int EPI>
__device__ __forceinline__ void gemm_dev(
    int bid, char* sm,
    const ushort* __restrict__ A, const ushort* __restrict__ Bt,
    const float* __restrict__ gf, const float* __restrict__ bias,
    ushort* __restrict__ outb, int ob_stride, int ob_off,
    ushort* __restrict__ outb2) {
  constexpr int T = WAVES * 64;
  constexpr int WRS = WAVES / 2;
  constexpr int RPW = BM / WRS;
  constexpr int MI = RPW / 16;
  constexpr int NFW = NCOL / 32;
  constexpr int A_BYTES = BM * 128;
  constexpr int B_BYTES = NCOL * 128;
  constexpr int NT2 = KZP / 64;
  constexpr int AI = (BM * 8) / T;
  constexpr int NB = NCOL * 8;
  constexpr int BI = (NB + T - 1) / T;
  static_assert(NCOL % 32 == 0 && KZP % 64 == 0 && RPW % 16 == 0 && (BM * 8) % T == 0, "geom");
  const int tid = threadIdx.x;
  const int lane = tid & 63, wid = tid >> 6;
  const int wr = wid >> 1, wc = wid & 1;
  const int g16 = lane >> 4;
  const int lane15 = lane & 15;
  const int e0 = bid * BM;
  const f32x4 vzero = {0.f, 0.f, 0.f, 0.f};

  const char* bSrc[BI];
#pragma unroll
  for (int it = 0; it < BI; ++it) {
    int q = tid + it * T;
    if (q < NB) {
      int c = q >> 3, ch = (q & 7) ^ (c & 7);
      bSrc[it] = (const char*)(Bt + (size_t)c * KZP) + ch * 16;
    } else bSrc[it] = nullptr;
  }

  f32x4 accS[MI][NFW];
#pragma unroll
  for (int mi = 0; mi < MI; ++mi)
#pragma unroll
    for (int n = 0; n < NFW; ++n) accS[mi][n] = vzero;

  if constexpr (NGRP > 1) {
    char* b_lds = sm;
    f32x4 accC[MI][NFW];
#pragma unroll
    for (int mi = 0; mi < MI; ++mi)
#pragma unroll
      for (int n = 0; n < NFW; ++n) accC[mi][n] = vzero;

    float gfr[MI][4];
    auto gf_pref = [&](int gx) {
#pragma unroll
      for (int mi = 0; mi < MI; ++mi)
#pragma unroll
        for (int j = 0; j < 4; ++j)
          gfr[mi][j] = gf[(size_t)(e0 + wr * RPW + mi * 16 + g16 * 4 + j) * 12 + gx];
    };
    gf_pref(0);

    bf16x8 afr[SPG2][MI][2];
#pragma unroll
    for (int wi = 0; wi < SPG2; ++wi)
#pragma unroll
      for (int mi = 0; mi < MI; ++mi)
#pragma unroll
        for (int s = 0; s < 2; ++s)
          afr[wi][mi][s] = *(const bf16x8*)(
              A + (size_t)(e0 + wr * RPW + mi * 16 + lane15) * ASTRIDE + FOFF +
              wi * 64 + s * 32 + g16 * 8);

    auto stageB = [&](int t2, int buf) {
#pragma unroll
      for (int it = 0; it < BI; ++it) {
        int q = tid + it * T;
        if (q < NB)
          gload16(bSrc[it] + (size_t)t2 * 128, b_lds + buf * B_BYTES + (tid - lane + it * T) * 16);
      }
    };

    // per-wave load count per batch (wave-uniform): FULLI or FULLI+1
    constexpr int FULLI = NB / T;
    constexpr int PARTW = (NB % T) / 64;  // waves [0,PARTW) carry one extra load
    auto wait_tail = [&](bool issued) {
      if (!issued) { wait_vm<0>(); return; }
      if constexpr ((NB % T) == 0) {
        wait_vm<FULLI>();
      } else {
        if (wid < PARTW) wait_vm<FULLI + 1>(); else wait_vm<FULLI>();
      }
    };

    // prologue: 2-deep prefetch, then wait batch0 (allow batch1 in flight)
    stageB(0, 0);
    stageB(1, 1);
    wait_tail(true);
    __builtin_amdgcn_s_barrier();
    asm volatile("" ::: "memory");

    for (int g = 0; g < NGRP; ++g) {
#pragma unroll
      for (int wi = 0; wi < SPG2; ++wi) {
        int t2 = g * SPG2 + wi;
        bool issue = (t2 + 2) < NT2;
        if (issue) stageB(t2 + 2, (t2 + 2) % 3);
        const char* bL = b_lds + (t2 % 3) * B_BYTES;
#pragma unroll
        for (int s = 0; s < 2; ++s) {
#pragma unroll
          for (int n = 0; n < NFW; ++n) {
            int cB = (wc * NFW + n) * 16 + lane15;
            int slot = (s * 4 + g16) ^ (cB & 7);
            bf16x8 b = *(const bf16x8*)(bL + cB * 128 + slot * 16);
#pragma unroll
            for (int mi = 0; mi < MI; ++mi)
              accC[mi][n] = __builtin_amdgcn_mfma_f32_16x16x32_bf16(afr[wi][mi][s], b, accC[mi][n], 0, 0, 0);
          }
        }
        if (wi == SPG2 - 1) {
#pragma unroll
          for (int mi = 0; mi < MI; ++mi)
#pragma unroll
            for (int n = 0; n < NFW; ++n) {
#pragma unroll
              for (int j = 0; j < 4; ++j) accS[mi][n][j] += gfr[mi][j] * accC[mi][n][j];
              accC[mi][n] = vzero;
            }
          if (g + 1 < NGRP) gf_pref(g + 1);
        }
        // counted wait: batches <= t2+1 complete; batch t2+2 stays in flight
        wait_tail(issue);
        __builtin_amdgcn_s_barrier();
        asm volatile("" ::: "memory");
      }
    }
  } else {
    char* a_lds = sm;
    char* b_lds = sm + 2 * A_BYTES;
    const char* aSrc[AI];
#pragma unroll
    for (int it = 0; it < AI; ++it) {
      int q = tid + it * T;
      int r = q >> 3, ch = (q & 7) ^ (r & 7);
      aSrc[it] = (const char*)(A + (size_t)(e0 + r) * ASTRIDE + FOFF) + ch * 16;
    }
    auto stage = [&](int t2, int buf) {
#pragma unroll
      for (int it = 0; it < AI; ++it)
        gload16(aSrc[it] + t2 * 128, a_lds + buf * A_BYTES + (tid - lane + it * T) * 16);
#pragma unroll
      for (int it = 0; it < BI; ++it) {
        int q = tid + it * T;
        if (q < NB)
          gload16(bSrc[it] + t2 * 128, b_lds + buf * B_BYTES + (tid - lane + it * T) * 16);
      }
    };
    stage(0, 0);
    __syncthreads();
    int cur = 0;
    for (int t2 = 0; t2 < NT2; ++t2) {
      if (t2 + 1 < NT2) stage(t2 + 1, cur ^ 1);
      const char* aL = a_lds + cur * A_BYTES;
      const char* bL = b_lds + cur * B_BYTES;
#pragma unroll
      for (int s = 0; s < 2; ++s) {
        bf16x8 a[MI];
#pragma unroll
        for (int mi = 0; mi < MI; ++mi) {
          int rA = wr * RPW + mi * 16 + lane15;
          int slot = (s * 4 + g16) ^ (rA & 7);
          a[mi] = *(const bf16x8*)(aL + rA * 128 + slot * 16);
        }
#pragma unroll
        for (int n = 0; n < NFW; ++n) {
          int cB = (wc * NFW + n) * 16 + lane15;
          int slot = (s * 4 + g16) ^ (cB & 7);
          bf16x8 b = *(const bf16x8*)(bL + cB * 128 + slot * 16);
#pragma unroll
          for (int mi = 0; mi < MI; ++mi)
            accS[mi][n] = __builtin_amdgcn_mfma_f32_16x16x32_bf16(a[mi], b, accS[mi][n], 0, 0, 0);
        }
      }
      __syncthreads();
      cur ^= 1;
    }
  }

#pragma unroll
  for (int mi = 0; mi < MI; ++mi) {
    const int row0 = wr * RPW + mi * 16 + g16 * 4;
#pragma unroll
    for (int n = 0; n < NFW; ++n) {
      const int c = (wc * NFW + n) * 16 + lane15;
      float bv = 0.f;
      if constexpr (HASBIAS) bv = bias[c];
#pragma unroll
      for (int j = 0; j < 4; ++j) {
        float v = accS[mi][n][j] + bv;
        const int er = e0 + row0 + j;
        if constexpr (EPI == 1) v = v / (1.f + __expf(-v));
        outb[(size_t)er * ob_stride + ob_off + c] = f2bf(v);
        if constexpr (EPI == 2) {
          if ((wc * NFW + n) * 16 < 64)
            outb2[(size_t)er * 256 + c] = f2bf(v / (1.f + __expf(-v)));
        }
      }
    }
  }
}

// ---- merged MoE GEMMs: one launch, 512-thread blocks (R17 geometry + 3-buf counted vmcnt) ----
struct MoeArgs {
  const ushort *f_all, *B0t, *B1t, *B2t;
  const float* gfb;
  ushort *moeout, *m2in;
};
__global__ __launch_bounds__(512) void k_moe(MoeArgs a) {
  __shared__ char sm[3 * 160 * 128 + 16];  // max B triple-buffer (moe0)
  int bid = blockIdx.x;
  if (bid < 512) {
    gemm_dev<8, 128, 3456, 6, 9, 160, 0, 832, false, 2>(
        bid, sm, a.f_all, a.B0t, a.gfb, nullptr, a.moeout, 288, 0, a.m2in);
  } else if (bid < 1024) {
    gemm_dev<8, 128, 2880, 5, 9, 96, 384, 832, false, 0>(
        bid - 512, sm, a.f_all, a.B1t, a.gfb, nullptr, a.moeout, 288, 160, nullptr);
  } else {
    gemm_dev<8, 128, 1152, 2, 9, 32, 704, 832, false, 0>(
        bid - 1024, sm, a.f_all, a.B2t, a.gfb, nullptr, a.moeout, 288, 256, nullptr);
  }
}

// ---- merged small GEMMs ----
struct Small3Args {
  const ushort *latbf, *Wet, *m2in, *Ttb, *P0t;
  const float* b0;
  ushort *wbuf, *tbuf, *m1in;
};
__global__ __launch_bounds__(256) void k_small3(Small3Args a) {
  __shared__ char sm[49168];
  int bid = blockIdx.x;
  if (bid < 1024) {
    gemm_dev<4, 64, 128, 1, 1, 128, 0, 128, false, 0>(
        bid, sm, a.latbf, a.Wet, nullptr, nullptr, a.wbuf, 128, 0, nullptr);
  } else if (bid < 2048) {
    gemm_dev<4, 64, 128, 1, 1, 128, 128, 256, false, 0>(
        bid - 1024, sm, a.m2in, a.Ttb, nullptr, nullptr, a.tbuf, 128, 0, nullptr);
  } else {
    gemm_dev<4, 64, 64, 1, 1, 64, 0, 256, true, 0>(
        bid - 2048, sm, a.m2in, a.P0t, nullptr, a.b0, a.m1in, 192, 128, nullptr);
  }
}

// --------- fused 6-layer MLP: 32 edges/block, X in LDS, W triple-buffered (counted vmcnt) ------
struct MlpArgs {
  const ushort *m1in, *m2in, *Wt1, *Wt2, *Wt3, *Wt4, *Wt5, *Wt6;
  const float *b1, *b2, *b3, *b4, *b5, *b6;
  const int* act;
  const float *cutg, *latg;
  float* out_lat;
};
__global__ __launch_bounds__(256) void k_mlp(MlpArgs A) {
  extern __shared__ char sm[];          // 77824 bytes (dynamic)
  char* Xa = sm;                        // 12288
  char* Xb = sm + 12288;                // 8192
  char* Xe = sm + 20480;                // 8192
  char* W0 = sm + 28672;                // 16384
  char* W1 = sm + 45056;                // 16384
  char* W2 = sm + 61440;                // 16384
  const int tid = threadIdx.x;
  const int lane = tid & 63, w = tid >> 6;
  const int wr = w >> 1, wc = w & 1;
  const int lane15 = lane & 15, g16 = lane >> 4;
  const int e32 = blockIdx.x * 32;
  const f32x4 vzero = {0.f, 0.f, 0.f, 0.f};

  auto stage_w = [&](const ushort* Wt, int K2, int t2, char* dst) {
#pragma unroll
    for (int it = 0; it < 4; ++it) {
      int q = tid + it * 256;
      int c = q >> 3, ch = (q & 7) ^ (c & 7);
      gload16((const char*)Wt + (size_t)c * K2 + t2 * 128 + ch * 16,
              dst + (w + it * 4) * 1024);
    }
  };
  {
#pragma unroll
    for (int it = 0; it < 3; ++it) {
      int q = tid + it * 256;
      int r = q / 24, c24 = q - r * 24;
      int t2 = c24 >> 3, ch = (c24 & 7) ^ (r & 7);
      gload16((const char*)A.m1in + (size_t)(e32 + r) * 384 + t2 * 128 + ch * 16,
              Xa + (w + it * 4) * 1024);
    }
#pragma unroll
    for (int it = 0; it < 2; ++it) {
      int q = tid + it * 256;
      int r = q >> 4, c16 = q & 15;
      int t2 = c16 >> 3, ch = (c16 & 7) ^ (r & 7);
      gload16((const char*)A.m2in + (size_t)(e32 + r) * 512 + 256 + t2 * 128 + ch * 16,
              Xe + (w + it * 4) * 1024);
    }
  }
  // prologue: 2-deep W prefetch (d0->W0, d1->W1); X loads are older and drain with d0.
  stage_w(A.Wt1, 384, 0, W0);
  stage_w(A.Wt1, 384, 1, W1);
  wait_vm<4>(); bar_lgkm();

  f32x4 acc[4];
#pragma unroll
  for (int n = 0; n < 4; ++n) acc[n] = vzero;

  auto compute = [&](const char* xin, int xstride, int t2loc, const char* wl) {
#pragma unroll
    for (int s = 0; s < 2; ++s) {
      int row = wr * 16 + lane15;
      bf16x8 a = *(const bf16x8*)(xin + row * xstride + t2loc * 128 + (((s * 4 + g16) ^ (row & 7)) << 4));
#pragma unroll
      for (int n = 0; n < 4; ++n) {
        int cB = wc * 64 + n * 16 + lane15;
        bf16x8 b = *(const bf16x8*)(wl + cB * 128 + (((s * 4 + g16) ^ (cB & 7)) << 4));
        acc[n] = __builtin_amdgcn_mfma_f32_16x16x32_bf16(a, b, acc[n], 0, 0, 0);
      }
    }
  };
  auto epi_x = [&](const float* bias, char* xout, int xstride, bool dosilu) {
#pragma unroll
    for (int n = 0; n < 4; ++n) {
      int c = wc * 64 + n * 16 + lane15;
      float bv = bias[c];
      int ch = (n * 16 + lane15) >> 3;
#pragma unroll
      for (int j = 0; j < 4; ++j) {
        int row = wr * 16 + g16 * 4 + j;
        float v = acc[n][j] + bv;
        if (dosilu) v = v / (1.f + __expf(-v));
        *(ushort*)(xout + row * xstride + wc * 128 + ((ch ^ (row & 7)) << 4) + ((lane15 & 7) << 1)) = f2bf(v);
      }
      acc[n] = vzero;
    }
  };

  // stages: data i -> buf i%3; stage_w at c_i stages data i+2; counted vmcnt(4) per stage.
  stage_w(A.Wt1, 384, 2, W2); compute(Xa, 384, 0, W0);                              wait_vm<4>(); bar_lgkm(); // c0
  stage_w(A.Wt2, 256, 0, W0); compute(Xa, 384, 1, W1);                              wait_vm<4>(); bar_lgkm(); // c1
  stage_w(A.Wt2, 256, 1, W1); compute(Xa, 384, 2, W2); epi_x(A.b1, Xb, 256, true);  wait_vm<4>(); bar_lgkm(); // c2
  stage_w(A.Wt3, 256, 0, W2); compute(Xb, 256, 0, W0);                              wait_vm<4>(); bar_lgkm(); // c3
  stage_w(A.Wt3, 256, 1, W0); compute(Xb, 256, 1, W1); epi_x(A.b2, Xa, 384, true);  wait_vm<4>(); bar_lgkm(); // c4
  stage_w(A.Wt4, 512, 0, W1); compute(Xa, 384, 0, W2);                              wait_vm<4>(); bar_lgkm(); // c5
  stage_w(A.Wt4, 512, 1, W2); compute(Xa, 384, 1, W0); epi_x(A.b3, Xb, 256, false); wait_vm<4>(); bar_lgkm(); // c6
  stage_w(A.Wt4, 512, 2, W0); compute(Xb, 256, 0, W1);                              wait_vm<4>(); bar_lgkm(); // c7
  stage_w(A.Wt4, 512, 3, W1); compute(Xb, 256, 1, W2);                              wait_vm<4>(); bar_lgkm(); // c8
  stage_w(A.Wt5, 256, 0, W2); compute(Xe, 256, 0, W0);                              wait_vm<4>(); bar_lgkm(); // c9
  stage_w(A.Wt5, 256, 1, W0); compute(Xe, 256, 1, W1); epi_x(A.b4, Xa, 384, true);  wait_vm<4>(); bar_lgkm(); // c10
  stage_w(A.Wt6, 256, 0, W1); compute(Xa, 384, 0, W2);                              wait_vm<4>(); bar_lgkm(); // c11
  stage_w(A.Wt6, 256, 1, W2); compute(Xa, 384, 1, W0); epi_x(A.b5, Xb, 256, true);  wait_vm<4>(); bar_lgkm(); // c12
  compute(Xb, 256, 0, W1);                                                          wait_vm<0>(); bar_lgkm(); // c13
  compute(Xb, 256, 1, W2);                                                                                    // c14
#pragma unroll
  for (int n = 0; n < 4; ++n) {
    int c = wc * 64 + n * 16 + lane15;
    float bv = A.b6[c];
#pragma unroll
    for (int j = 0; j < 4; ++j) {
      int row = wr * 16 + g16 * 4 + j;
      int er = e32 + row;
      int ae = A.act[er];
      float v = acc[n][j] + bv;
      A.out_lat[(size_t)ae * 128 + c] = C_NEW * A.cutg[ae] * v + C_OLD * A.latg[(size_t)ae * 128 + c];
    }
  }
}

// ------ post-MoE + final combine: wave-per-edge, 8 edges/block; P-mixes via 3 MFMAs ------
__global__ __launch_bounds__(512) void k_postf(
    const ushort* __restrict__ moeout,
    const float* __restrict__ D1g, const float* __restrict__ D2g,
    const float* __restrict__ latg, const int* __restrict__ act,
    const float* __restrict__ P1, const float* __restrict__ P2,
    const ushort* __restrict__ wbuf, const float* __restrict__ beg,
    const float* __restrict__ lng, const float* __restrict__ lnb,
    const ushort* __restrict__ tbufp, const float* __restrict__ efg,
    ushort* __restrict__ m1in, float* __restrict__ out_edge) {
  __shared__ float SM[1136 + 8 * 920];
  ushort* Btab = (ushort*)SM;
  float* be_s = SM + 768;
  float* lng_s = SM + 880;
  float* lnb_s = SM + 1008;
  const int t = threadIdx.x;
  const int w = t >> 6, lane = t & 63;
  float* Wp = SM + 1136 + w * 920;
  float* o   = Wp;
  float* row = Wp + 224;
  float* sg  = Wp + 464;
  float* d1  = Wp + 512;
  float* d2  = Wp + 524;
  ushort* wvh = (ushort*)(Wp + 552);
  ushort* tvh = (ushort*)(Wp + 608);
  ushort* tile = (ushort*)(Wp + 664);
  const int e = blockIdx.x * 8 + w;
  const int ae = act[e];
  const f32x4 vzero = {0.f, 0.f, 0.f, 0.f};

  float ef[4];
  ef[0] = efg[(size_t)e * 240 + lane];
  ef[1] = efg[(size_t)e * 240 + 64 + lane];
  ef[2] = efg[(size_t)e * 240 + 128 + lane];
  ef[3] = (lane < 48) ? efg[(size_t)e * 240 + 192 + lane] : 0.f;
  float2v ll = ((const float2v*)(latg + (size_t)ae * 128))[lane];

  if (lane < 28) {
    uintx4 raw = *(const uintx4*)(moeout + (size_t)e * 288 + 64 + lane * 8);
    float* dst = o + lane * 8;
#pragma unroll
    for (int j = 0; j < 4; ++j) {
      uint u = raw[j];
      dst[2 * j] = bf2f((ushort)(u & 0xFFFF));
      dst[2 * j + 1] = bf2f((ushort)(u >> 16));
    }
  }
  if (lane < 14) {
    *(uintx4*)((char*)wvh + lane * 16) = *(const uintx4*)(wbuf + (size_t)e * 128 + lane * 8);
    *(uintx4*)((char*)tvh + lane * 16) = *(const uintx4*)(tbufp + (size_t)e * 128 + lane * 8);
  }
  if (lane < 8) {
    uintx4 raw = *(const uintx4*)(m1in + (size_t)e * 192 + 128 + lane * 8);
    float* dst = row + lane * 8;
#pragma unroll
    for (int j = 0; j < 4; ++j) {
      uint u = raw[j];
      dst[2 * j] = bf2f((ushort)(u & 0xFFFF));
      dst[2 * j + 1] = bf2f((ushort)(u >> 16));
    }
  }
  if (lane < 9)  d1[lane] = D1g[(size_t)e * 9 + lane];
  if (lane < 25) d2[lane] = D2g[(size_t)e * 25 + lane];
  if (lane < 48) sg[lane] = 1.f / (1.f + __expf(-o[lane]));

#pragma unroll
  for (int i = 0; i < 3; ++i) {
    int q = t + i * 512;
    int tbl = q >> 9, idx = q & 511;
    int d = idx >> 5, c = idx & 31;
    float v;
    if (tbl == 0) v = P1[c * 32 + d];
    else if (tbl == 1) v = P1[c * 32 + 16 + d];
    else v = (c < 16) ? P2[c * 16 + d] : 0.f;
    Btab[tbl * 512 + d * 32 + (((c >> 3) ^ (d & 3)) << 3) + (c & 7)] = f2bf(v);
  }
  if (t < 368) {
    if (t < 112) be_s[t] = beg[t];
    else if (t < 240) lng_s[t - 112] = lng[t - 112];
    else lnb_s[t - 240] = lnb[t - 240];
  }

  float sum = ll[0] + ll[1];
  float sq = ll[0] * ll[0] + ll[1] * ll[1];
#pragma unroll
  for (int m = 32; m > 0; m >>= 1) {
    sum += __shfl_xor(sum, m);
    sq += __shfl_xor(sq, m);
  }
  const float mu = sum * (1.f / 128.f);
  const float rs = rsqrtf(sq * (1.f / 128.f) - mu * mu + 1e-5f);

  __syncthreads();

  {
    int i = 2 * lane;
    float l0 = (ll[0] - mu) * rs * lng_s[i] + lnb_s[i];
    float l1 = (ll[1] - mu) * rs * lng_s[i + 1] + lnb_s[i + 1];
    ((uint*)m1in)[(size_t)e * 96 + lane] = (uint)f2bf(l0) | ((uint)f2bf(l1) << 16);
  }
#pragma unroll
  for (int rr = 0; rr < 2; ++rr) {
    int r = lane + rr * 64;
    if (r < 96) {
      int m = r >> 5, c = r & 31;
      float v = d1[m] * o[144 + c] + d1[3 + m] * o[48 + c] + d1[6 + m] * o[96 + c];
      tile[m * 32 + (((c >> 3) ^ (m & 3)) << 3) + (c & 7)] = f2bf(v * sg[c]);
    }
  }
#pragma unroll
  for (int rr = 0; rr < 3; ++rr) {
    int r = lane + rr * 64;
    if (r < 160) {
      int rw = 3 + (r >> 5), c = r & 31;
      ushort hv = 0;
      if (c < 16) {
        int m = rw - 3;
        float v = d2[m] * o[208 + c] + d2[5 + m] * o[176 + c] + d2[10 + m] * o[80 + c] +
                  d2[15 + m] * o[128 + c] + d2[20 + m] * o[192 + c];
        hv = f2bf(v * sg[32 + c]);
      }
      tile[rw * 32 + (((c >> 3) ^ (rw & 3)) << 3) + (c & 7)] = hv;
    }
  }
  {
    const int r15 = lane & 15, g = lane >> 4;
    const int fslot = (g ^ (r15 & 3)) << 3;
    bf16x8 afr = *(const bf16x8*)(tile + r15 * 32 + fslot);
    bf16x8 b1a = *(const bf16x8*)(Btab + r15 * 32 + fslot);
    bf16x8 b1b = *(const bf16x8*)(Btab + 512 + r15 * 32 + fslot);
    bf16x8 b2p = *(const bf16x8*)(Btab + 1024 + r15 * 32 + fslot);
    f32x4 v1a = __builtin_amdgcn_mfma_f32_16x16x32_bf16(afr, b1a, vzero, 0, 0, 0);
    f32x4 v1b = __builtin_amdgcn_mfma_f32_16x16x32_bf16(afr, b1b, vzero, 0, 0, 0);
    f32x4 v2r = __builtin_amdgcn_mfma_f32_16x16x32_bf16(afr, b2p, vzero, 0, 0, 0);
    if (g == 0) {
      float s1 = bf2f(wvh[64 + r15]) + be_s[64 + r15];
      row[64 + r15 * 3 + 0] = v1a[0] * s1;
      row[64 + r15 * 3 + 1] = v1a[1] * s1;
      row[64 + r15 * 3 + 2] = v1a[2] * s1;
      float s2 = bf2f(wvh[80 + r15]) + be_s[80 + r15];
      row[64 + (16 + r15) * 3 + 0] = v1b[0] * s2;
      row[64 + (16 + r15) * 3 + 1] = v1b[1] * s2;
      row[64 + (16 + r15) * 3 + 2] = v1b[2] * s2;
      float s3 = bf2f(wvh[96 + r15]) + be_s[96 + r15];
      row[160 + r15 * 5 + 0] = v2r[3] * s3;
    } else if (g == 1) {
      float s3 = bf2f(wvh[96 + r15]) + be_s[96 + r15];
      row[160 + r15 * 5 + 1] = v2r[0] * s3;
      row[160 + r15 * 5 + 2] = v2r[1] * s3;
      row[160 + r15 * 5 + 3] = v2r[2] * s3;
      row[160 + r15 * 5 + 4] = v2r[3] * s3;
    }
  }
  row[lane] = row[lane] * (bf2f(wvh[lane]) + be_s[lane]);
#pragma unroll
  for (int r = 0; r < 4; ++r) {
    int d = lane + r * 64;
    if (r < 3 || lane < 48) {
      float v = C_OLD * ef[r] + C_NEW * row[d];
      int ti = (d < 64) ? d : (d < 160) ? 64 + (d - 64) / 3 : 96 + (d - 160) / 5;
      float f = bf2f(tvh[ti]) * T_SCALE;
      out_edge[(size_t)e * 240 + d] = v * (1.f + f);
    }
  }
}

extern "C" void kernel_launch(void* const* d_in, const int* in_sizes, int n_in,
                              void* d_out, int out_size, void* d_ws, size_t ws_size,
                              hipStream_t stream) {
  const float* latents = (const float*)d_in[0];
  const float* node_f  = (const float*)d_in[1];
  const float* edge_f  = (const float*)d_in[3];
  const float* cutoff  = (const float*)d_in[5];
  const float* eoh     = (const float*)d_in[6];
  const float* D1      = (const float*)d_in[7];
  const float* D2      = (const float*)d_in[8];
  const float* mg      = (const float*)d_in[9];
  const int*   eidx    = (const int*)d_in[10];
  const int*   act     = (const int*)d_in[11];
  const float* Wg      = (const float*)d_in[12];
  const float* W0      = (const float*)d_in[13];
  const float* W1r     = (const float*)d_in[14];
  const float* W1i     = (const float*)d_in[15];
  const float* W2r     = (const float*)d_in[16];
  const float* W2i     = (const float*)d_in[17];
  const float* P0      = (const float*)d_in[18];
  const float* b0      = (const float*)d_in[19];
  const float* P1      = (const float*)d_in[20];
  const float* P2      = (const float*)d_in[21];
  const float* We      = (const float*)d_in[22];
  const float* be      = (const float*)d_in[23];
  const float* lng     = (const float*)d_in[24];
  const float* lnb     = (const float*)d_in[25];
  const float* M1W0_   = (const float*)d_in[26];
  const float* M1b0_   = (const float*)d_in[27];
  const float* M1W1_   = (const float*)d_in[28];
  const float* M1b1_   = (const float*)d_in[29];
  const float* M1W2_   = (const float*)d_in[30];
  const float* M1b2_   = (const float*)d_in[31];
  const float* M2W0_   = (const float*)d_in[32];
  const float* M2b0_   = (const float*)d_in[33];
  const float* M2W1_   = (const float*)d_in[34];
  const float* M2b1_   = (const float*)d_in[35];
  const float* M2W2_   = (const float*)d_in[36];
  const float* M2b2_   = (const float*)d_in[37];
  const float* T0      = (const float*)d_in[38];
  const float* T1      = (const float*)d_in[39];
  const float* T2      = (const float*)d_in[40];

  float* out_edge = (float*)d_out;
  float* out_lat  = out_edge + (size_t)EDGES * 240;
  float* out_d1   = out_lat + (size_t)EDGES * 128;
  float* out_d2   = out_d1 + (size_t)EDGES * 9;

  char* ws = (char*)d_ws;
  size_t off = 0;
  auto alloc = [&](size_t bytes) -> char* {
    char* p = ws + off;
    off += (bytes + 255) & ~size_t(255);
    return p;
  };
  ushort* f_all  = (ushort*)alloc((size_t)EDGES * 832 * 2);
  float*  gfb    = (float*) alloc((size_t)EDGES * 12 * 4);
  ushort* moeout = (ushort*)alloc((size_t)EDGES * 288 * 2);
  ushort* m2in   = (ushort*)alloc((size_t)EDGES * 256 * 2);
  ushort* latbf  = (ushort*)alloc((size_t)EDGES * 128 * 2);
  ushort* wbuf   = (ushort*)alloc((size_t)EDGES * 128 * 2);
  ushort* B0t    = (ushort*)alloc(160 * 3456 * 2);
  ushort* B1t    = (ushort*)alloc(96 * 2880 * 2);
  ushort* B2t    = (ushort*)alloc(32 * 1152 * 2);
  ushort* Wt1    = (ushort*)alloc(128 * 192 * 2);
  ushort* Wt2    = (ushort*)alloc(128 * 128 * 2);
  ushort* Wt3    = (ushort*)alloc(128 * 128 * 2);
  ushort* Wt4    = (ushort*)alloc(128 * 256 * 2);
  ushort* Wt5    = (ushort*)alloc(128 * 128 * 2);
  ushort* Wt6    = (ushort*)alloc(128 * 128 * 2);
  ushort* Wet    = (ushort*)alloc(128 * 128 * 2);
  ushort* Ttb    = (ushort*)alloc(128 * 128 * 2);
  ushort* P0t    = (ushort*)alloc(64 * 64 * 2);

  ushort* m1in = f_all;   // E*192 overlay (dead after MoE GEMMs)
  ushort* tbuf = latbf;   // reused after We-GEMM

  if (ws_size < off) return;

  // one-time: allow >64KB dynamic LDS for k_mlp (host-side attribute, not a stream op)
  static bool mlp_attr_set = false;
  if (!mlp_attr_set) {
    hipFuncSetAttribute(reinterpret_cast<const void*>(k_mlp),
                        hipFuncAttributeMaxDynamicSharedMemorySize, 77824);
    mlp_attr_set = true;
  }

  // merged front: pack (blocks [0,4008)) + prep w/ D1,D2 passthrough (blocks [4008,20392))
  PackArgs pk = {W0, W1r, W1i, W2r, W2i,
                 M1W0_, M1W1_, M1W2_, M2W0_, M2W1_, M2W2_, We, T0, T1, T2, P0,
                 B0t, B1t, B2t,
                 Wt1, Wt2, Wt3, Wt4, Wt5, Wt6, Wet, Ttb, P0t};
  k_front<<<PACK_BLOCKS + EDGES / 4, 256, 0, stream>>>(
      pk, node_f, edge_f, D1, D2, mg, Wg, latents, eoh, eidx, act,
      f_all, gfb, latbf, m2in, out_d1, out_d2);

  // merged MoE GEMMs: BM=128, 8 waves/block, 3-buf counted-vmcnt pipeline
  MoeArgs mo = {f_all, B0t, B1t, B2t, gfb, moeout, m2in};
  k_moe<<<1536, 512, 0, stream>>>(mo);

  // merged small GEMMs: lat@We | eoh@T^T | scs@P0+b0 in one launch
  Small3Args s3 = {latbf, Wet, m2in, Ttb, P0t, b0, wbuf, tbuf, m1in};
  k_small3<<<3072, 256, 0, stream>>>(s3);

  // fused post + final combine (wave-per-edge, 8 edges/block, MFMA P-mixes)
  k_postf<<<EDGES / 8, 512, 0, stream>>>(moeout, D1, D2, latents, act, P1, P2,
                                         wbuf, be, lng, lnb, tbuf, edge_f, m1in, out_edge);

  // fused 6-layer MLP chain (W triple-buffer, counted vmcnt; final layer fuses latent update)
  MlpArgs ma = {m1in, m2in, Wt1, Wt2, Wt3, Wt4, Wt5, Wt6,
                M1b0_, M1b1_, M1b2_, M2b0_, M2b1_, M2b2_,
                act, cutoff, latents, out_lat};
  k_mlp<<<EDGES / 32, 256, 77824, stream>>>(ma);
}